// Round 10
// baseline (451.975 us; speedup 1.0000x reference)
//
#include <hip/hip_runtime.h>
#include <math.h>

#define NEG_SLOPE 0.2f
#define BN_EPS 1e-5f

typedef __attribute__((ext_vector_type(8))) short bf16x8;
typedef __attribute__((ext_vector_type(4))) float f32x4;
typedef unsigned short u16;
typedef __attribute__((ext_vector_type(4))) unsigned short u16x4;

static __device__ __forceinline__ float leaky(float v) { return v > 0.f ? v : NEG_SLOPE * v; }
static __device__ __forceinline__ float b2f(u16 b) { return __uint_as_float(((unsigned)b) << 16); }
static __device__ __forceinline__ u16 f2b(float f) {
  unsigned u = __float_as_uint(f);
  u += 0x7FFF + ((u >> 16) & 1);
  return (u16)(u >> 16);
}
static __device__ __forceinline__ float sel4(f32x4 v, int hs) {
  float a = (hs & 1) ? v[1] : v[0];
  float b = (hs & 1) ? v[3] : v[2];
  return (hs & 2) ? b : a;
}

#define PREP_ITEMS 172352
#define PREP_BLOCKS 674  // ceil(172352/256)

// ---------------- mega front-end: weight prep | degree count | x cast + L1 dots ----------------
__global__ __launch_bounds__(256) void k_mega(
    const float* __restrict__ W1, const float* __restrict__ W2, const float* __restrict__ W3,
    const float* __restrict__ AS1, const float* __restrict__ AD1,
    const float* __restrict__ WE1, const float* __restrict__ AE1,
    const float* __restrict__ WE2, const float* __restrict__ AE2,
    const float* __restrict__ WE3, const float* __restrict__ AE3,
    u16* __restrict__ Wt1, u16* __restrict__ Wt2, u16* __restrict__ Wt3,
    float* __restrict__ ws1, float* __restrict__ wd1,
    float* __restrict__ watt1, float* __restrict__ watt2, float* __restrict__ watt3,
    const int* __restrict__ dst, int* __restrict__ degInt, int E, int degB,
    const float* __restrict__ x, u16* __restrict__ xbf,
    float* __restrict__ asrc, float* __restrict__ adst, int Nn) {
  int bid = blockIdx.x;
  int tid = threadIdx.x;
  if (bid < PREP_BLOCKS) {
    int idx = bid * 256 + tid;
    if (idx < 32768) {                       // Wt1 [512][64] <- W1 [64][512]
      int k = idx >> 9, n = idx & 511;
      Wt1[n * 64 + k] = f2b(W1[idx]);
    } else if (idx < 163840) {               // Wt2 [256][512] <- W2 [512][256]
      int i = idx - 32768;
      int k = i >> 8, n = i & 255;
      Wt2[n * 512 + k] = f2b(W2[i]);
    } else if (idx < 172032) {               // Wt3 [32][256] <- W3 [256][32]
      int i = idx - 163840;
      int k = i >> 5, n = i & 31;
      Wt3[n * 256 + k] = f2b(W3[i]);
    } else if (idx < 172288) {               // ws1/wd1 [64][4]
      int t = idx - 172032;
      int k = t >> 2, h = t & 3;
      float s1 = 0.f, s2 = 0.f;
      for (int c = 0; c < 128; c++) {
        float w = W1[k * 512 + h * 128 + c];
        s1 += w * AS1[h * 128 + c];
        s2 += w * AD1[h * 128 + c];
      }
      ws1[t] = s1; wd1[t] = s2;
    } else if (idx < 172316) {               // watt1 [7][4]
      int t = idx - 172288;
      int d = t >> 2, h = t & 3;
      float s = 0.f;
      for (int c = 0; c < 128; c++) s += WE1[d * 512 + h * 128 + c] * AE1[h * 128 + c];
      watt1[t] = s;
    } else if (idx < 172344) {               // watt2 [7][4]
      int t = idx - 172316;
      int d = t >> 2, h = t & 3;
      float s = 0.f;
      for (int c = 0; c < 64; c++) s += WE2[d * 256 + h * 64 + c] * AE2[h * 64 + c];
      watt2[t] = s;
    } else if (idx < 172351) {               // watt3 [7]
      int d = idx - 172344;
      float s = 0.f;
      for (int c = 0; c < 32; c++) s += WE3[d * 32 + c] * AE3[c];
      watt3[d] = s;
    }
  } else if (bid < PREP_BLOCKS + degB) {
    int e = (bid - PREP_BLOCKS) * 256 + tid;
    if (e < E) atomicAdd(&degInt[dst[e]], 1);
  } else {
    int n = (bid - PREP_BLOCKS - degB) * 4 + (tid >> 6);
    if (n >= Nn) return;
    int lane = tid & 63;
    float xv = x[(size_t)n * 64 + lane];
    xbf[(size_t)n * 64 + lane] = f2b(xv);
    f32x4 vs = *(const f32x4*)(ws1 + lane * 4);   // note: ws1/wd1 are SMALL; written by prep blocks
    f32x4 vd = *(const f32x4*)(wd1 + lane * 4);   // of THIS kernel? No - see driver: ws1/wd1 passed
    f32x4 s1, s2;                                 // precomputed? They are computed in prep range...
#pragma unroll
    for (int h = 0; h < 4; h++) { s1[h] = xv * vs[h]; s2[h] = xv * vd[h]; }
#pragma unroll
    for (int off = 1; off < 64; off <<= 1) {
#pragma unroll
      for (int h = 0; h < 4; h++) { s1[h] += __shfl_xor(s1[h], off); s2[h] += __shfl_xor(s2[h], off); }
    }
    if (lane == 0) {
      *(f32x4*)(asrc + n * 4) = s1;
      *(f32x4*)(adst + n * 4) = s2;
    }
  }
}

// ws/wd for L1 dots must exist BEFORE k_mega's cast range (no intra-kernel ordering) ->
// compute them inline per cast wave instead: cheap alternative kernel below is used when needed.
// To keep ordering safe, the cast range above must NOT read ws1/wd1 produced by prep blocks.
// Therefore the driver computes ws1/wd1 via this tiny kernel BEFORE k_mega? That re-adds a launch.
// Instead: cast waves compute the dot directly against W1/AS1/AD1? Too heavy.
// Resolution: cast range reads ws1/wd1 computed in a PREVIOUS launch is unnecessary --
// we instead fold ws1/wd1 computation INTO the cast waves cheaply via LDS: each cast block
// (256 threads) computes ws1/wd1 into LDS once (64x4 dots of length 128 = 32K MACs per block).
// That is ~128 MACs/thread: acceptable. Implemented in k_cast_attn_x_lds below; k_mega's cast
// range is DISABLED by passing castB=0 ws-dependent... simpler: keep cast INSIDE k_mega but
// compute ws/wd per-block in LDS (no cross-block dependency).

__global__ __launch_bounds__(256) void k_mega2(
    const float* __restrict__ W1, const float* __restrict__ W2, const float* __restrict__ W3,
    const float* __restrict__ AS1, const float* __restrict__ AD1,
    const float* __restrict__ WE1, const float* __restrict__ AE1,
    const float* __restrict__ WE2, const float* __restrict__ AE2,
    const float* __restrict__ WE3, const float* __restrict__ AE3,
    u16* __restrict__ Wt1, u16* __restrict__ Wt2, u16* __restrict__ Wt3,
    float* __restrict__ watt1, float* __restrict__ watt2, float* __restrict__ watt3,
    const int* __restrict__ dst, int* __restrict__ degInt, int E, int degB,
    const float* __restrict__ x, u16* __restrict__ xbf,
    float* __restrict__ asrc, float* __restrict__ adst, int Nn) {
  int bid = blockIdx.x;
  int tid = threadIdx.x;
  if (bid < PREP_BLOCKS) {
    int idx = bid * 256 + tid;
    if (idx < 32768) {
      int k = idx >> 9, n = idx & 511;
      Wt1[n * 64 + k] = f2b(W1[idx]);
    } else if (idx < 163840) {
      int i = idx - 32768;
      int k = i >> 8, n = i & 255;
      Wt2[n * 512 + k] = f2b(W2[i]);
    } else if (idx < 172032) {
      int i = idx - 163840;
      int k = i >> 5, n = i & 31;
      Wt3[n * 256 + k] = f2b(W3[i]);
    } else if (idx < 172060) {               // watt1 [7][4]
      int t = idx - 172032;
      int d = t >> 2, h = t & 3;
      float s = 0.f;
      for (int c = 0; c < 128; c++) s += WE1[d * 512 + h * 128 + c] * AE1[h * 128 + c];
      watt1[t] = s;
    } else if (idx < 172088) {               // watt2 [7][4]
      int t = idx - 172060;
      int d = t >> 2, h = t & 3;
      float s = 0.f;
      for (int c = 0; c < 64; c++) s += WE2[d * 256 + h * 64 + c] * AE2[h * 64 + c];
      watt2[t] = s;
    } else if (idx < 172095) {               // watt3 [7]
      int d = idx - 172088;
      float s = 0.f;
      for (int c = 0; c < 32; c++) s += WE3[d * 32 + c] * AE3[c];
      watt3[d] = s;
    }
  } else if (bid < PREP_BLOCKS + degB) {
    int e = (bid - PREP_BLOCKS) * 256 + tid;
    if (e < E) atomicAdd(&degInt[dst[e]], 1);
  } else {
    // cast + L1 dots; ws/wd computed per-block into LDS (no cross-block dependency)
    __shared__ float lws[256], lwd[256];
    {
      int t = tid;  // t = k*4+h, k in [0,64), h in [0,4)
      int k = t >> 2, h = t & 3;
      float s1 = 0.f, s2 = 0.f;
      for (int c = 0; c < 128; c++) {
        float w = W1[k * 512 + h * 128 + c];
        s1 += w * AS1[h * 128 + c];
        s2 += w * AD1[h * 128 + c];
      }
      lws[t] = s1; lwd[t] = s2;
    }
    __syncthreads();
    int n = (bid - PREP_BLOCKS - degB) * 4 + (tid >> 6);
    if (n >= Nn) return;
    int lane = tid & 63;
    float xv = x[(size_t)n * 64 + lane];
    xbf[(size_t)n * 64 + lane] = f2b(xv);
    f32x4 vs = *(const f32x4*)(lws + lane * 4);
    f32x4 vd = *(const f32x4*)(lwd + lane * 4);
    f32x4 s1, s2;
#pragma unroll
    for (int h = 0; h < 4; h++) { s1[h] = xv * vs[h]; s2[h] = xv * vd[h]; }
#pragma unroll
    for (int off = 1; off < 64; off <<= 1) {
#pragma unroll
      for (int h = 0; h < 4; h++) { s1[h] += __shfl_xor(s1[h], off); s2[h] += __shfl_xor(s2[h], off); }
    }
    if (lane == 0) {
      *(f32x4*)(asrc + n * 4) = s1;
      *(f32x4*)(adst + n * 4) = s2;
    }
  }
}

// ---------------- CSR ----------------
__global__ void k_scan(const int* __restrict__ degInt, int* __restrict__ rowStart, int n) {
  __shared__ int sums[1024];
  int tid = threadIdx.x;
  int per = (n + 1023) / 1024;
  int start = tid * per;
  int end = start + per; if (end > n) end = n;
  int s = 0;
  for (int i = start; i < end; i++) s += degInt[i];
  sums[tid] = s;
  __syncthreads();
  for (int off = 1; off < 1024; off <<= 1) {
    int v = (tid >= off) ? sums[tid - off] : 0;
    __syncthreads();
    sums[tid] += v;
    __syncthreads();
  }
  int base = (tid > 0) ? sums[tid - 1] : 0;
  for (int i = start; i < end; i++) { rowStart[i] = base; base += degInt[i]; }
  if (tid == 1023) rowStart[n] = sums[1023];
}

__global__ void k_fill_csr_ae(const int* __restrict__ src, const int* __restrict__ dst,
                              const float* __restrict__ eattr,
                              const int* __restrict__ rowStart, int* __restrict__ cursor,
                              int* __restrict__ csrSrc,
                              const float* __restrict__ watt1, const float* __restrict__ watt2,
                              const float* __restrict__ watt3,
                              float* __restrict__ ae1, float* __restrict__ ae2,
                              float* __restrict__ ae3, int E) {
  int e = blockIdx.x * blockDim.x + threadIdx.x;
  if (e >= E) return;
  int d = dst[e];
  int pos = rowStart[d] + atomicAdd(&cursor[d], 1);
  csrSrc[pos] = src[e];
  float ea[7];
#pragma unroll
  for (int dd = 0; dd < 7; dd++) ea[dd] = eattr[e * 7 + dd];
  f32x4 o1, o2;
#pragma unroll
  for (int h = 0; h < 4; h++) {
    float a1 = 0.f, a2 = 0.f;
#pragma unroll
    for (int dd = 0; dd < 7; dd++) { a1 += ea[dd] * watt1[dd * 4 + h]; a2 += ea[dd] * watt2[dd * 4 + h]; }
    o1[h] = a1; o2[h] = a2;
  }
  float a3 = 0.f;
#pragma unroll
  for (int dd = 0; dd < 7; dd++) a3 += ea[dd] * watt3[dd];
  *(f32x4*)(ae1 + (size_t)pos * 4) = o1;
  *(f32x4*)(ae2 + (size_t)pos * 4) = o2;
  ae3[pos] = a3;
}

// ---------------- MFMA bf16 GEMM with optional epilogue / fused attn dots ----------------
template <int BM, int BN, int WM, int WN, bool EPI, int ATTN_H>
__global__ __launch_bounds__(256) void k_gemm_mfma(const u16* __restrict__ A,
                                                   const u16* __restrict__ Bt,
                                                   u16* __restrict__ Cout,
                                                   int M, int K, int Nc, int lda, int ldc,
                                                   int AzOff, int BzOff, int CzOff,
                                                   const float* __restrict__ bias,
                                                   const float* __restrict__ bng,
                                                   const float* __restrict__ bnb,
                                                   const float* __restrict__ bnrm,
                                                   const float* __restrict__ bnrv,
                                                   const float* __restrict__ a_s,
                                                   const float* __restrict__ a_d,
                                                   float* __restrict__ asrc,
                                                   float* __restrict__ adst) {
  constexpr int BK = 64;
  constexpr int LDT = BK + 8;
  __shared__ u16 As[BM][LDT];
  __shared__ u16 Bs[BN][LDT];
  constexpr int NWN = BN / WN;
  constexpr int M_REP = WM / 16;
  constexpr int N_REP = WN / 16;
  int z = blockIdx.z;
  A += (size_t)z * AzOff;
  Bt += (size_t)z * BzOff;
  Cout += (size_t)z * CzOff;
  if (EPI) {
    bias += (size_t)z * CzOff; bng += (size_t)z * CzOff; bnb += (size_t)z * CzOff;
    bnrm += (size_t)z * CzOff; bnrv += (size_t)z * CzOff;
  }
  int tid = threadIdx.x;
  int wid = tid >> 6, lane = tid & 63;
  int wr = wid / NWN, wc = wid % NWN;
  int bm = blockIdx.x * BM, bn = blockIdx.y * BN;
  int l15 = lane & 15, l4 = lane >> 4;

  f32x4 acc[M_REP][N_REP];
#pragma unroll
  for (int m = 0; m < M_REP; m++)
#pragma unroll
    for (int n = 0; n < N_REP; n++) acc[m][n] = (f32x4){0.f, 0.f, 0.f, 0.f};

  for (int k0 = 0; k0 < K; k0 += BK) {
    constexpr int CHA = BM * BK / 8;
#pragma unroll
    for (int ch0 = 0; ch0 < CHA; ch0 += 256) {
      int ch = ch0 + tid;
      int row = ch >> 3, cc = (ch & 7) * 8;
      int gr = bm + row;
      bf16x8 v = {};
      if (gr < M) v = *(const bf16x8*)(A + (size_t)gr * lda + k0 + cc);
      *(bf16x8*)(&As[row][cc]) = v;
    }
    constexpr int CHB = BN * BK / 8;
#pragma unroll
    for (int ch0 = 0; ch0 < CHB; ch0 += 256) {
      int ch = ch0 + tid;
      int row = ch >> 3, cc = (ch & 7) * 8;
      int gr = bn + row;
      bf16x8 v = {};
      if (gr < Nc) v = *(const bf16x8*)(Bt + (size_t)gr * K + k0 + cc);
      *(bf16x8*)(&Bs[row][cc]) = v;
    }
    __syncthreads();
#pragma unroll
    for (int ks = 0; ks < BK; ks += 32) {
      bf16x8 af[M_REP], bfr[N_REP];
#pragma unroll
      for (int m = 0; m < M_REP; m++)
        af[m] = *(const bf16x8*)(&As[wr * WM + m * 16 + l15][ks + l4 * 8]);
#pragma unroll
      for (int n = 0; n < N_REP; n++)
        bfr[n] = *(const bf16x8*)(&Bs[wc * WN + n * 16 + l15][ks + l4 * 8]);
#pragma unroll
      for (int m = 0; m < M_REP; m++)
#pragma unroll
        for (int n = 0; n < N_REP; n++)
          acc[m][n] = __builtin_amdgcn_mfma_f32_16x16x32_bf16(af[m], bfr[n], acc[m][n], 0, 0, 0);
    }
    __syncthreads();
  }
#pragma unroll
  for (int m = 0; m < M_REP; m++) {
#pragma unroll
    for (int r = 0; r < 4; r++) {
      int grow = bm + wr * WM + m * 16 + l4 * 4 + r;
      if (grow >= M) continue;
#pragma unroll
      for (int n = 0; n < N_REP; n++) {
        int gcol = bn + wc * WN + n * 16 + l15;
        if (gcol >= Nc) continue;
        float v = acc[m][n][r];
        if (EPI) {
          v += bias[gcol];
          v = (v - bnrm[gcol]) * (bng[gcol] * rsqrtf(bnrv[gcol] + BN_EPS)) + bnb[gcol];
          v = fmaxf(v, 0.f);
        }
        Cout[(size_t)grow * ldc + gcol] = f2b(v);
      }
    }
  }
  if (ATTN_H > 0) {
    int h = blockIdx.y * NWN + wc;
#pragma unroll
    for (int m = 0; m < M_REP; m++) {
#pragma unroll
      for (int r = 0; r < 4; r++) {
        float s1 = 0.f, s2 = 0.f;
#pragma unroll
        for (int n = 0; n < N_REP; n++) {
          float av = acc[m][n][r];
          int cc = n * 16 + l15;
          s1 += av * a_s[h * WN + cc];
          s2 += av * a_d[h * WN + cc];
        }
#pragma unroll
        for (int off = 1; off < 16; off <<= 1) { s1 += __shfl_xor(s1, off); s2 += __shfl_xor(s2, off); }
        int grow = bm + wr * WM + m * 16 + l4 * 4 + r;
        if (l15 == 0 && grow < M) {
          asrc[grow * ATTN_H + h] = s1;
          adst[grow * ATTN_H + h] = s2;
        }
      }
    }
  }
}

// ---------------- L1 gather in x-space ----------------
__global__ __launch_bounds__(256) void k_gather_x(
    const int* __restrict__ rowStart, const int* __restrict__ csrSrc,
    const float* __restrict__ aeC, const float* __restrict__ asrc, const float* __restrict__ adst,
    const u16* __restrict__ xbf, u16* __restrict__ aggOut, int Nn) {
  int wid = threadIdx.x >> 6;
  int n = blockIdx.x * 4 + wid;
  if (n >= Nn) return;
  int lane = threadIdx.x & 63;
  __shared__ float pbuf[4][64 * 4];
  int r0 = rowStart[n], r1 = rowStart[n + 1];
  f32x4 vaN = *(const f32x4*)(asrc + n * 4);
  f32x4 vdN = *(const f32x4*)(adst + n * 4);

  f32x4 m = {-1e30f, -1e30f, -1e30f, -1e30f};
  f32x4 denl = {0.f, 0.f, 0.f, 0.f};
  f32x4 aes = {0.f, 0.f, 0.f, 0.f};
  f32x4 acc = {0.f, 0.f, 0.f, 0.f};

  const f32x4* AE4 = (const f32x4*)aeC;
  for (int base = r0; base < r1; base += 64) {
    int slot = base + lane;
    bool valid = slot < r1;
    int srcl = 0;
    f32x4 lg = {-1e30f, -1e30f, -1e30f, -1e30f};
    if (valid) {
      srcl = csrSrc[slot];
      f32x4 vaS = *(const f32x4*)(asrc + srcl * 4);
      f32x4 ae = AE4[slot];
#pragma unroll
      for (int h = 0; h < 4; h++) { aes[h] += ae[h]; lg[h] = leaky(vaS[h] + vdN[h] + ae[h]); }
    }
    f32x4 mc = lg;
#pragma unroll
    for (int off = 1; off < 64; off <<= 1) {
#pragma unroll
      for (int h = 0; h < 4; h++) mc[h] = fmaxf(mc[h], __shfl_xor(mc[h], off));
    }
    f32x4 rr;
#pragma unroll
    for (int h = 0; h < 4; h++) {
      float mn = fmaxf(m[h], mc[h]);
      rr[h] = __expf(m[h] - mn);
      m[h] = mn;
      denl[h] *= rr[h];
      acc[h] *= rr[h];
    }
    f32x4 ex;
#pragma unroll
    for (int h = 0; h < 4; h++) ex[h] = valid ? __expf(lg[h] - m[h]) : 0.f;
#pragma unroll
    for (int h = 0; h < 4; h++) denl[h] += ex[h];
    *(f32x4*)(&pbuf[wid][lane * 4]) = ex;
    int nv = r1 - base; if (nv > 64) nv = 64;
    int j = 0;
    for (; j + 7 < nv; j += 8) {
      int ss[8];
      float xs[8];
#pragma unroll
      for (int q = 0; q < 8; q++) ss[q] = __shfl(srcl, j + q);
#pragma unroll
      for (int q = 0; q < 8; q++) xs[q] = b2f(xbf[(size_t)ss[q] * 64 + lane]);
#pragma unroll
      for (int q = 0; q < 8; q++) {
        f32x4 p = *(const f32x4*)(&pbuf[wid][(j + q) * 4]);
#pragma unroll
        for (int h = 0; h < 4; h++) acc[h] += p[h] * xs[q];
      }
    }
    for (; j < nv; j++) {
      int s0 = __shfl(srcl, j);
      f32x4 p0 = *(const f32x4*)(&pbuf[wid][j * 4]);
      float x0 = b2f(xbf[(size_t)s0 * 64 + lane]);
#pragma unroll
      for (int h = 0; h < 4; h++) acc[h] += p0[h] * x0;
    }
  }
  float degf = fmaxf((float)(r1 - r0), 1.0f);
  f32x4 ls, exs;
#pragma unroll
  for (int h = 0; h < 4; h++) {
    float a = aes[h];
#pragma unroll
    for (int off = 1; off < 64; off <<= 1) a += __shfl_xor(a, off);
    ls[h] = leaky(vaN[h] + vdN[h] + a / degf);
    float mn = fmaxf(m[h], ls[h]);
    float sc = __expf(m[h] - mn);
    m[h] = mn;
    denl[h] *= sc;
    acc[h] *= sc;
    exs[h] = __expf(ls[h] - mn);
  }
  f32x4 den;
#pragma unroll
  for (int h = 0; h < 4; h++) {
    float v = denl[h];
#pragma unroll
    for (int off = 1; off < 64; off <<= 1) v += __shfl_xor(v, off);
    den[h] = v + exs[h];
  }
  {
    float xn = b2f(xbf[(size_t)n * 64 + lane]);
#pragma unroll
    for (int h = 0; h < 4; h++) acc[h] += exs[h] * xn;
  }
#pragma unroll
  for (int h = 0; h < 4; h++) pbuf[wid][h * 64 + lane] = acc[h] / den[h];
  u16x4 ov;
#pragma unroll
  for (int jj = 0; jj < 4; jj++) ov[jj] = f2b(pbuf[wid][lane * 4 + jj]);
  *(u16x4*)(aggOut + (size_t)n * 256 + lane * 4) = ov;
}

// ---------------- gather (H=4) post-GEMM ----------------
template <int C, int CPL>
__global__ __launch_bounds__(256) void k_gather4(
    const int* __restrict__ rowStart, const int* __restrict__ csrSrc,
    const float* __restrict__ aeC, const float* __restrict__ asrc, const float* __restrict__ adst,
    const u16* __restrict__ hbuf, const float* __restrict__ bias,
    const float* __restrict__ bng, const float* __restrict__ bnb,
    const float* __restrict__ bnrm, const float* __restrict__ bnrv,
    u16* __restrict__ outbuf, int Nn) {
  constexpr int HC = 4 * C;
  typedef __attribute__((ext_vector_type(CPL))) unsigned short u16v;
  int wid = threadIdx.x >> 6;
  int n = blockIdx.x * 4 + wid;
  if (n >= Nn) return;
  int lane = threadIdx.x & 63;
  int hs = lane >> 4;
  __shared__ float pbuf[4][64 * 4];
  int r0 = rowStart[n], r1 = rowStart[n + 1];
  f32x4 vaN = *(const f32x4*)(asrc + n * 4);
  f32x4 vdN = *(const f32x4*)(adst + n * 4);

  f32x4 m = {-1e30f, -1e30f, -1e30f, -1e30f};
  f32x4 denl = {0.f, 0.f, 0.f, 0.f};
  f32x4 aes = {0.f, 0.f, 0.f, 0.f};
  float acc[CPL];
#pragma unroll
  for (int jj = 0; jj < CPL; jj++) acc[jj] = 0.f;

  const f32x4* AE4 = (const f32x4*)aeC;
  for (int base = r0; base < r1; base += 64) {
    int slot = base + lane;
    bool valid = slot < r1;
    int srcl = 0;
    f32x4 lg = {-1e30f, -1e30f, -1e30f, -1e30f};
    if (valid) {
      srcl = csrSrc[slot];
      f32x4 vaS = *(const f32x4*)(asrc + srcl * 4);
      f32x4 ae = AE4[slot];
#pragma unroll
      for (int h = 0; h < 4; h++) { aes[h] += ae[h]; lg[h] = leaky(vaS[h] + vdN[h] + ae[h]); }
    }
    f32x4 mc = lg;
#pragma unroll
    for (int off = 1; off < 64; off <<= 1) {
#pragma unroll
      for (int h = 0; h < 4; h++) mc[h] = fmaxf(mc[h], __shfl_xor(mc[h], off));
    }
    f32x4 rr;
#pragma unroll
    for (int h = 0; h < 4; h++) {
      float mn = fmaxf(m[h], mc[h]);
      rr[h] = __expf(m[h] - mn);
      m[h] = mn;
      denl[h] *= rr[h];
    }
    float rrh = sel4(rr, hs);
#pragma unroll
    for (int jj = 0; jj < CPL; jj++) acc[jj] *= rrh;
    f32x4 ex;
#pragma unroll
    for (int h = 0; h < 4; h++) ex[h] = valid ? __expf(lg[h] - m[h]) : 0.f;
#pragma unroll
    for (int h = 0; h < 4; h++) denl[h] += ex[h];
    *(f32x4*)(&pbuf[wid][lane * 4]) = ex;
    int nv = r1 - base; if (nv > 64) nv = 64;
    int j = 0;
    for (; j + 7 < nv; j += 8) {
      int ss[8];
#pragma unroll
      for (int q = 0; q < 8; q++) ss[q] = __shfl(srcl, j + q);
      u16v hv[8];
#pragma unroll
      for (int q = 0; q < 8; q++) hv[q] = *(const u16v*)(hbuf + (size_t)ss[q] * HC + lane * CPL);
#pragma unroll
      for (int q = 0; q < 8; q++) {
        float p = pbuf[wid][(j + q) * 4 + hs];
#pragma unroll
        for (int jj = 0; jj < CPL; jj++) acc[jj] += p * b2f(hv[q][jj]);
      }
    }
    for (; j < nv; j++) {
      int s0 = __shfl(srcl, j);
      float p0 = pbuf[wid][j * 4 + hs];
      u16v h0 = *(const u16v*)(hbuf + (size_t)s0 * HC + lane * CPL);
#pragma unroll
      for (int jj = 0; jj < CPL; jj++) acc[jj] += p0 * b2f(h0[jj]);
    }
  }
  float degf = fmaxf((float)(r1 - r0), 1.0f);
  f32x4 ls, exs, scv;
#pragma unroll
  for (int h = 0; h < 4; h++) {
    float a = aes[h];
#pragma unroll
    for (int off = 1; off < 64; off <<= 1) a += __shfl_xor(a, off);
    ls[h] = leaky(vaN[h] + vdN[h] + a / degf);
    float mn = fmaxf(m[h], ls[h]);
    scv[h] = __expf(m[h] - mn);
    m[h] = mn;
    denl[h] *= scv[h];
    exs[h] = __expf(ls[h] - mn);
  }
  float sch = sel4(scv, hs);
#pragma unroll
  for (int jj = 0; jj < CPL; jj++) acc[jj] *= sch;
  f32x4 den;
#pragma unroll
  for (int h = 0; h < 4; h++) {
    float v = denl[h];
#pragma unroll
    for (int off = 1; off < 64; off <<= 1) v += __shfl_xor(v, off);
    den[h] = v + exs[h];
  }
  {
    float ps = sel4(exs, hs);
    u16v hN = *(const u16v*)(hbuf + (size_t)n * HC + lane * CPL);
#pragma unroll
    for (int jj = 0; jj < CPL; jj++) acc[jj] += ps * b2f(hN[jj]);
  }
  float dh = sel4(den, hs);
  u16v ov;
#pragma unroll
  for (int jj = 0; jj < CPL; jj++) {
    int c = lane * CPL + jj;
    float v = acc[jj] / dh + bias[c];
    v = (v - bnrm[c]) * (bng[c] * rsqrtf(bnrv[c] + BN_EPS)) + bnb[c];
    ov[jj] = f2b(fmaxf(v, 0.f));
  }
  *(u16v*)(outbuf + (size_t)n * HC + lane * CPL) = ov;
}

// ---------------- gather (H=1, C=32), online single-pass ----------------
__global__ __launch_bounds__(256) void k_gather_L3(
    const int* __restrict__ rowStart, const int* __restrict__ csrSrc,
    const float* __restrict__ ae3, const float* __restrict__ asrc, const float* __restrict__ adst,
    const u16* __restrict__ hbuf, const float* __restrict__ bias,
    const float* __restrict__ bng, const float* __restrict__ bnb,
    const float* __restrict__ bnrm, const float* __restrict__ bnrv,
    u16* __restrict__ outbuf, int Nn) {
  int wid = threadIdx.x >> 6;
  int n = blockIdx.x * 4 + wid;
  if (n >= Nn) return;
  int lane = threadIdx.x & 63;
  int cl = lane & 31, half = lane >> 5;
  __shared__ float pbuf[4][64];
  int r0 = rowStart[n], r1 = rowStart[n + 1];
  float vaN = asrc[n], vdN = adst[n];

  float m = -1e30f, denl = 0.f, aes = 0.f, acc = 0.f;
  for (int base = r0; base < r1; base += 64) {
    int slot = base + lane;
    bool valid = slot < r1;
    int srcl = 0;
    float lg = -1e30f;
    if (valid) {
      srcl = csrSrc[slot];
      float ae = ae3[slot];
      aes += ae;
      lg = leaky(asrc[srcl] + vdN + ae);
    }
    float mc = lg;
#pragma unroll
    for (int off = 1; off < 64; off <<= 1) mc = fmaxf(mc, __shfl_xor(mc, off));
    float mn = fmaxf(m, mc);
    float sc = __expf(m - mn);
    m = mn;
    denl *= sc;
    acc *= sc;
    float ex = valid ? __expf(lg - m) : 0.f;
    denl += ex;
    pbuf[wid][lane] = ex;
    int nv = r1 - base; if (nv > 64) nv = 64;
    for (int j = half; j < nv; j += 2) {
      float p = pbuf[wid][j];
      int s = __shfl(srcl, j);
      acc += p * b2f(hbuf[(size_t)s * 32 + cl]);
    }
  }
#pragma unroll
  for (int off = 1; off < 64; off <<= 1) aes += __shfl_xor(aes, off);
  float degf = fmaxf((float)(r1 - r0), 1.0f);
  float ls = leaky(vaN + vdN + aes / degf);
  float mn = fmaxf(m, ls);
  float sc = __expf(m - mn);
  denl *= sc;
  acc *= sc;
  float exs = __expf(ls - mn);
#pragma unroll
  for (int off = 1; off < 64; off <<= 1) denl += __shfl_xor(denl, off);
  float den = denl + exs;
  if (half == 0) acc += exs * b2f(hbuf[(size_t)n * 32 + cl]);
  acc += __shfl_xor(acc, 32);
  if (half == 0) {
    float v = acc / den + bias[cl];
    v = (v - bnrm[cl]) * (bng[cl] * rsqrtf(bnrv[cl] + BN_EPS)) + bnb[cl];
    outbuf[(size_t)n * 32 + cl] = f2b(fmaxf(v, 0.f));
  }
}

// ---------------- fused pooling + MLP ----------------
__global__ __launch_bounds__(256) void k_pool_mlp(
    const u16* __restrict__ h3, const int* __restrict__ batch, int Nn,
    const float* __restrict__ lw1, const float* __restrict__ lb1,
    const float* __restrict__ lw2, const float* __restrict__ lb2,
    float* __restrict__ out) {
  int g = blockIdx.x;
  int tid = threadIdx.x;
  __shared__ int s_lo, s_hi;
  if (tid == 0) {
    int lo = 0, hi = Nn;
    while (lo < hi) { int mid = (lo + hi) >> 1; if (batch[mid] < g) lo = mid + 1; else hi = mid; }
    s_lo = lo;
    int lo2 = lo, hi2 = Nn;
    while (lo2 < hi2) { int mid = (lo2 + hi2) >> 1; if (batch[mid] < g + 1) lo2 = mid + 1; else hi2 = mid; }
    s_hi = lo2;
  }
  __syncthreads();
  int lo = s_lo, hi = s_hi;
  int c = tid & 31, r = tid >> 5;
  float sum = 0.f, mx = -1e30f;
  for (int n = lo + r; n < hi; n += 8) {
    float v = b2f(h3[(size_t)n * 32 + c]);
    sum += v;
    mx = fmaxf(mx, v);
  }
  __shared__ float ssum[8][32];
  __shared__ float smax[8][32];
  ssum[r][c] = sum;
  smax[r][c] = mx;
  __syncthreads();
  __shared__ float z[64];
  __shared__ float zz1[32];
  if (tid < 32) {
    float s = 0.f, m2 = -1e30f;
#pragma unroll
    for (int rr = 0; rr < 8; rr++) { s += ssum[rr][tid]; m2 = fmaxf(m2, smax[rr][tid]); }
    int cnt = hi - lo;
    z[tid] = s / fmaxf((float)cnt, 1.0f);
    z[32 + tid] = (cnt > 0) ? m2 : 0.f;
  }
  __syncthreads();
  if (tid < 32) {
    float s = lb1[tid];
    for (int k = 0; k < 64; k++) s += z[k] * lw1[k * 32 + tid];
    zz1[tid] = fmaxf(s, 0.f);
  }
  __syncthreads();
  if (tid == 0) {
    float s = lb2[0];
    for (int j = 0; j < 32; j++) s += zz1[j] * lw2[j];
    out[g] = 1.f / (1.f + expf(-s));
  }
}

// ---------------- driver ----------------
extern "C" void kernel_launch(void* const* d_in, const int* in_sizes, int n_in,
                              void* d_out, int out_size, void* d_ws, size_t ws_size,
                              hipStream_t stream) {
  const float* x     = (const float*)d_in[0];
  const int*   eidx  = (const int*)d_in[1];
  const float* eattr = (const float*)d_in[2];
  const int*   batch = (const int*)d_in[3];
  int N = in_sizes[0] / 64;
  int E = in_sizes[1] / 2;
  int NG = out_size;
  const int* src = eidx;
  const int* dst = eidx + E;

  const float* W[3]  = {(const float*)d_in[4],  (const float*)d_in[14], (const float*)d_in[24]};
  const float* AS[3] = {(const float*)d_in[5],  (const float*)d_in[15], (const float*)d_in[25]};
  const float* AD[3] = {(const float*)d_in[6],  (const float*)d_in[16], (const float*)d_in[26]};
  const float* WE[3] = {(const float*)d_in[7],  (const float*)d_in[17], (const float*)d_in[27]};
  const float* AE[3] = {(const float*)d_in[8],  (const float*)d_in[18], (const float*)d_in[28]};
  const float* B[3]  = {(const float*)d_in[9],  (const float*)d_in[19], (const float*)d_in[29]};
  const float* G[3]  = {(const float*)d_in[10], (const float*)d_in[20], (const float*)d_in[30]};
  const float* BT[3] = {(const float*)d_in[11], (const float*)d_in[21], (const float*)d_in[31]};
  const float* RM[3] = {(const float*)d_in[12], (const float*)d_in[22], (const float*)d_in[32]};
  const float* RV[3] = {(const float*)d_in[13], (const float*)d_in[23], (const float*)d_in[33]};
  const float* lw1 = (const float*)d_in[34];
  const float* lb1 = (const float*)d_in[35];
  const float* lw2 = (const float*)d_in[36];
  const float* lb2 = (const float*)d_in[37];

  char* wp = (char*)d_ws;
  auto alloc = [&](size_t bytes) -> void* {
    void* p = (void*)wp;
    wp += (bytes + 255) & ~(size_t)255;
    return p;
  };
  u16*   xbf      = (u16*)alloc((size_t)N * 64 * 2);
  u16*   aggB     = (u16*)alloc((size_t)N * 256 * 2);
  u16*   bufH     = (u16*)alloc((size_t)N * 512 * 2);
  u16*   bufA     = (u16*)alloc((size_t)N * 512 * 2);
  u16*   Wt1      = (u16*)alloc((size_t)512 * 64 * 2);
  u16*   Wt2      = (u16*)alloc((size_t)256 * 512 * 2);
  u16*   Wt3      = (u16*)alloc((size_t)32 * 256 * 2);
  int*   degInt   = (int*)alloc((size_t)N * 4);
  int*   cursor   = (int*)alloc((size_t)N * 4);
  int*   rowStart = (int*)alloc((size_t)(N + 1) * 4);
  int*   csrSrc   = (int*)alloc((size_t)E * 4);
  float* ae1      = (float*)alloc((size_t)E * 4 * 4);
  float* ae2      = (float*)alloc((size_t)E * 4 * 4);
  float* ae3buf   = (float*)alloc((size_t)E * 4);
  float* asrc     = (float*)alloc((size_t)N * 4 * 4);
  float* adst     = (float*)alloc((size_t)N * 4 * 4);
  float* watt1    = (float*)alloc(28 * 4);
  float* watt2    = (float*)alloc(28 * 4);
  float* watt3    = (float*)alloc(7 * 4);

  // one memset covers degInt (+pad) + cursor (adjacent allocations)
  size_t zspan = (size_t)((char*)cursor - (char*)degInt) + (size_t)N * 4;
  hipMemsetAsync(degInt, 0, zspan, stream);

  int degB = (E + 255) / 256;
  int nb4 = (N + 3) / 4;
  int megaBlocks = PREP_BLOCKS + degB + nb4;

  // ---- mega front-end: weight prep | degree | x-cast + L1 dots (independent work, one launch)
  k_mega2<<<megaBlocks, 256, 0, stream>>>(
      W[0], W[1], W[2], AS[0], AD[0], WE[0], AE[0], WE[1], AE[1], WE[2], AE[2],
      Wt1, Wt2, Wt3, watt1, watt2, watt3,
      dst, degInt, E, degB, x, xbf, asrc, adst, N);

  // ---- CSR build + fused edge-ae scatter
  k_scan<<<1, 1024, 0, stream>>>(degInt, rowStart, N);
  k_fill_csr_ae<<<(E + 255) / 256, 256, 0, stream>>>(src, dst, eattr, rowStart, cursor, csrSrc,
                                                     watt1, watt2, watt3, ae1, ae2, ae3buf, E);

  int gmM = (N + 127) / 128;

  // ---- layer 1: x-space aggregation, then 4 head-GEMMs with fused epilogue
  k_gather_x<<<nb4, 256, 0, stream>>>(rowStart, csrSrc, ae1, asrc, adst, xbf, aggB, N);
  k_gemm_mfma<128, 128, 64, 64, true, 0><<<dim3(gmM, 1, 4), 256, 0, stream>>>(
      aggB, Wt1, bufA, N, 64, 128, 256, 512, 64, 128 * 64, 128,
      B[0], G[0], BT[0], RM[0], RV[0], nullptr, nullptr, nullptr, nullptr);

  // ---- layer 2: GEMM with fused attn dots (WN=64=C), then gather
  k_gemm_mfma<128, 128, 64, 64, false, 4><<<dim3(gmM, 2, 1), 256, 0, stream>>>(
      bufA, Wt2, bufH, N, 512, 256, 512, 256, 0, 0, 0,
      nullptr, nullptr, nullptr, nullptr, nullptr, AS[1], AD[1], asrc, adst);
  k_gather4<64, 4><<<nb4, 256, 0, stream>>>(rowStart, csrSrc, ae2, asrc, adst,
                                            bufH, B[1], G[1], BT[1], RM[1], RV[1], bufA, N);

  // ---- layer 3: GEMM with fused attn dots (WN=32=C, H=1), then gather
  k_gemm_mfma<128, 32, 32, 32, false, 1><<<dim3(gmM, 1, 1), 256, 0, stream>>>(
      bufA, Wt3, bufH, N, 256, 32, 256, 32, 0, 0, 0,
      nullptr, nullptr, nullptr, nullptr, nullptr, AS[2], AD[2], asrc, adst);
  k_gather_L3<<<nb4, 256, 0, stream>>>(rowStart, csrSrc, ae3buf, asrc, adst,
                                       bufH, B[2], G[2], BT[2], RM[2], RV[2], bufA, N);

  // ---- fused pooling + MLP
  k_pool_mlp<<<NG, 256, 0, stream>>>(bufA, batch, N, lw1, lb1, lw2, lb2, (float*)d_out);
}

// Round 11
// 270.171 us; speedup vs baseline: 1.6729x; 1.6729x over previous
//
#include <hip/hip_runtime.h>
#include <math.h>

#define NEG_SLOPE 0.2f
#define BN_EPS 1e-5f

typedef __attribute__((ext_vector_type(8))) short bf16x8;
typedef __attribute__((ext_vector_type(4))) float f32x4;
typedef unsigned short u16;
typedef __attribute__((ext_vector_type(4))) unsigned short u16x4;

static __device__ __forceinline__ float leaky(float v) { return v > 0.f ? v : NEG_SLOPE * v; }
static __device__ __forceinline__ float b2f(u16 b) { return __uint_as_float(((unsigned)b) << 16); }
static __device__ __forceinline__ u16 f2b(float f) {
  unsigned u = __float_as_uint(f);
  u += 0x7FFF + ((u >> 16) & 1);
  return (u16)(u >> 16);
}
static __device__ __forceinline__ float sel4(f32x4 v, int hs) {
  float a = (hs & 1) ? v[1] : v[0];
  float b = (hs & 1) ? v[3] : v[2];
  return (hs & 2) ? b : a;
}

// ---------------- prep: weight transposes + attn-weight projections (ONE pass, computed once) ----------------
__global__ void k_prep(const float* __restrict__ W1, const float* __restrict__ W2, const float* __restrict__ W3,
                       const float* __restrict__ AS1, const float* __restrict__ AD1,
                       const float* __restrict__ WE1, const float* __restrict__ AE1,
                       const float* __restrict__ WE2, const float* __restrict__ AE2,
                       const float* __restrict__ WE3, const float* __restrict__ AE3,
                       u16* __restrict__ Wt1, u16* __restrict__ Wt2, u16* __restrict__ Wt3,
                       float* __restrict__ ws1, float* __restrict__ wd1,
                       float* __restrict__ watt1, float* __restrict__ watt2, float* __restrict__ watt3) {
  int idx = blockIdx.x * blockDim.x + threadIdx.x;
  if (idx < 32768) {                       // Wt1 [512][64] <- W1 [64][512]
    int k = idx >> 9, n = idx & 511;
    Wt1[n * 64 + k] = f2b(W1[idx]);
  } else if (idx < 163840) {               // Wt2 [256][512] <- W2 [512][256]
    int i = idx - 32768;
    int k = i >> 8, n = i & 255;
    Wt2[n * 512 + k] = f2b(W2[i]);
  } else if (idx < 172032) {               // Wt3 [32][256] <- W3 [256][32]
    int i = idx - 163840;
    int k = i >> 5, n = i & 31;
    Wt3[n * 256 + k] = f2b(W3[i]);
  } else if (idx < 172288) {               // ws1/wd1 [64][4]
    int t = idx - 172032;
    int k = t >> 2, h = t & 3;
    float s1 = 0.f, s2 = 0.f;
    for (int c = 0; c < 128; c++) {
      float w = W1[k * 512 + h * 128 + c];
      s1 += w * AS1[h * 128 + c];
      s2 += w * AD1[h * 128 + c];
    }
    ws1[t] = s1; wd1[t] = s2;
  } else if (idx < 172316) {               // watt1 [7][4]
    int t = idx - 172288;
    int d = t >> 2, h = t & 3;
    float s = 0.f;
    for (int c = 0; c < 128; c++) s += WE1[d * 512 + h * 128 + c] * AE1[h * 128 + c];
    watt1[t] = s;
  } else if (idx < 172344) {               // watt2 [7][4]
    int t = idx - 172316;
    int d = t >> 2, h = t & 3;
    float s = 0.f;
    for (int c = 0; c < 64; c++) s += WE2[d * 256 + h * 64 + c] * AE2[h * 64 + c];
    watt2[t] = s;
  } else if (idx < 172351) {               // watt3 [7]
    int d = idx - 172344;
    float s = 0.f;
    for (int c = 0; c < 32; c++) s += WE3[d * 32 + c] * AE3[c];
    watt3[d] = s;
  }
}

// ---------------- CSR build ----------------
__global__ void k_deg(const int* __restrict__ dst, int* __restrict__ degInt, int E) {
  int e = blockIdx.x * blockDim.x + threadIdx.x;
  if (e < E) atomicAdd(&degInt[dst[e]], 1);
}

__global__ void k_scan(const int* __restrict__ degInt, int* __restrict__ rowStart, int n) {
  __shared__ int sums[1024];
  int tid = threadIdx.x;
  int per = (n + 1023) / 1024;
  int start = tid * per;
  int end = start + per; if (end > n) end = n;
  int s = 0;
  for (int i = start; i < end; i++) s += degInt[i];
  sums[tid] = s;
  __syncthreads();
  for (int off = 1; off < 1024; off <<= 1) {
    int v = (tid >= off) ? sums[tid - off] : 0;
    __syncthreads();
    sums[tid] += v;
    __syncthreads();
  }
  int base = (tid > 0) ? sums[tid - 1] : 0;
  for (int i = start; i < end; i++) { rowStart[i] = base; base += degInt[i]; }
  if (tid == 1023) rowStart[n] = sums[1023];
}

// fill CSR AND scatter all 9 head ae-slots in one edge pass
__global__ void k_fill_csr_ae(const int* __restrict__ src, const int* __restrict__ dst,
                              const float* __restrict__ eattr,
                              const int* __restrict__ rowStart, int* __restrict__ cursor,
                              int* __restrict__ csrSrc,
                              const float* __restrict__ watt1, const float* __restrict__ watt2,
                              const float* __restrict__ watt3,
                              float* __restrict__ ae1, float* __restrict__ ae2,
                              float* __restrict__ ae3, int E) {
  int e = blockIdx.x * blockDim.x + threadIdx.x;
  if (e >= E) return;
  int d = dst[e];
  int pos = rowStart[d] + atomicAdd(&cursor[d], 1);
  csrSrc[pos] = src[e];
  float ea[7];
#pragma unroll
  for (int dd = 0; dd < 7; dd++) ea[dd] = eattr[e * 7 + dd];
  f32x4 o1, o2;
#pragma unroll
  for (int h = 0; h < 4; h++) {
    float a1 = 0.f, a2 = 0.f;
#pragma unroll
    for (int dd = 0; dd < 7; dd++) { a1 += ea[dd] * watt1[dd * 4 + h]; a2 += ea[dd] * watt2[dd * 4 + h]; }
    o1[h] = a1; o2[h] = a2;
  }
  float a3 = 0.f;
#pragma unroll
  for (int dd = 0; dd < 7; dd++) a3 += ea[dd] * watt3[dd];
  *(f32x4*)(ae1 + (size_t)pos * 4) = o1;
  *(f32x4*)(ae2 + (size_t)pos * 4) = o2;
  ae3[pos] = a3;
}

// ---------------- fused x cast + L1 attention dots (ws/wd precomputed by k_prep) ----------------
__global__ __launch_bounds__(256) void k_cast_attn_x(const float* __restrict__ x, u16* __restrict__ xbf,
                                                     const float* __restrict__ ws, const float* __restrict__ wd,
                                                     float* __restrict__ asrc, float* __restrict__ adst, int Nn) {
  int n = blockIdx.x * 4 + (threadIdx.x >> 6);
  if (n >= Nn) return;
  int lane = threadIdx.x & 63;
  float xv = x[(size_t)n * 64 + lane];
  xbf[(size_t)n * 64 + lane] = f2b(xv);
  f32x4 vs = *(const f32x4*)(ws + lane * 4);
  f32x4 vd = *(const f32x4*)(wd + lane * 4);
  f32x4 s1, s2;
#pragma unroll
  for (int h = 0; h < 4; h++) { s1[h] = xv * vs[h]; s2[h] = xv * vd[h]; }
#pragma unroll
  for (int off = 1; off < 64; off <<= 1) {
#pragma unroll
    for (int h = 0; h < 4; h++) { s1[h] += __shfl_xor(s1[h], off); s2[h] += __shfl_xor(s2[h], off); }
  }
  if (lane == 0) {
    *(f32x4*)(asrc + n * 4) = s1;
    *(f32x4*)(adst + n * 4) = s2;
  }
}

// ---------------- MFMA bf16 GEMM with optional epilogue / fused attn dots ----------------
template <int BM, int BN, int WM, int WN, bool EPI, int ATTN_H>
__global__ __launch_bounds__(256) void k_gemm_mfma(const u16* __restrict__ A,
                                                   const u16* __restrict__ Bt,
                                                   u16* __restrict__ Cout,
                                                   int M, int K, int Nc, int lda, int ldc,
                                                   int AzOff, int BzOff, int CzOff,
                                                   const float* __restrict__ bias,
                                                   const float* __restrict__ bng,
                                                   const float* __restrict__ bnb,
                                                   const float* __restrict__ bnrm,
                                                   const float* __restrict__ bnrv,
                                                   const float* __restrict__ a_s,
                                                   const float* __restrict__ a_d,
                                                   float* __restrict__ asrc,
                                                   float* __restrict__ adst) {
  constexpr int BK = 64;
  constexpr int LDT = BK + 8;
  __shared__ u16 As[BM][LDT];
  __shared__ u16 Bs[BN][LDT];
  constexpr int NWN = BN / WN;
  constexpr int M_REP = WM / 16;
  constexpr int N_REP = WN / 16;
  int z = blockIdx.z;
  A += (size_t)z * AzOff;
  Bt += (size_t)z * BzOff;
  Cout += (size_t)z * CzOff;
  if (EPI) {
    bias += (size_t)z * CzOff; bng += (size_t)z * CzOff; bnb += (size_t)z * CzOff;
    bnrm += (size_t)z * CzOff; bnrv += (size_t)z * CzOff;
  }
  int tid = threadIdx.x;
  int wid = tid >> 6, lane = tid & 63;
  int wr = wid / NWN, wc = wid % NWN;
  int bm = blockIdx.x * BM, bn = blockIdx.y * BN;
  int l15 = lane & 15, l4 = lane >> 4;

  f32x4 acc[M_REP][N_REP];
#pragma unroll
  for (int m = 0; m < M_REP; m++)
#pragma unroll
    for (int n = 0; n < N_REP; n++) acc[m][n] = (f32x4){0.f, 0.f, 0.f, 0.f};

  for (int k0 = 0; k0 < K; k0 += BK) {
    constexpr int CHA = BM * BK / 8;
#pragma unroll
    for (int ch0 = 0; ch0 < CHA; ch0 += 256) {
      int ch = ch0 + tid;
      int row = ch >> 3, cc = (ch & 7) * 8;
      int gr = bm + row;
      bf16x8 v = {};
      if (gr < M) v = *(const bf16x8*)(A + (size_t)gr * lda + k0 + cc);
      *(bf16x8*)(&As[row][cc]) = v;
    }
    constexpr int CHB = BN * BK / 8;
#pragma unroll
    for (int ch0 = 0; ch0 < CHB; ch0 += 256) {
      int ch = ch0 + tid;
      int row = ch >> 3, cc = (ch & 7) * 8;
      int gr = bn + row;
      bf16x8 v = {};
      if (gr < Nc) v = *(const bf16x8*)(Bt + (size_t)gr * K + k0 + cc);
      *(bf16x8*)(&Bs[row][cc]) = v;
    }
    __syncthreads();
#pragma unroll
    for (int ks = 0; ks < BK; ks += 32) {
      bf16x8 af[M_REP], bfr[N_REP];
#pragma unroll
      for (int m = 0; m < M_REP; m++)
        af[m] = *(const bf16x8*)(&As[wr * WM + m * 16 + l15][ks + l4 * 8]);
#pragma unroll
      for (int n = 0; n < N_REP; n++)
        bfr[n] = *(const bf16x8*)(&Bs[wc * WN + n * 16 + l15][ks + l4 * 8]);
#pragma unroll
      for (int m = 0; m < M_REP; m++)
#pragma unroll
        for (int n = 0; n < N_REP; n++)
          acc[m][n] = __builtin_amdgcn_mfma_f32_16x16x32_bf16(af[m], bfr[n], acc[m][n], 0, 0, 0);
    }
    __syncthreads();
  }
#pragma unroll
  for (int m = 0; m < M_REP; m++) {
#pragma unroll
    for (int r = 0; r < 4; r++) {
      int grow = bm + wr * WM + m * 16 + l4 * 4 + r;
      if (grow >= M) continue;
#pragma unroll
      for (int n = 0; n < N_REP; n++) {
        int gcol = bn + wc * WN + n * 16 + l15;
        if (gcol >= Nc) continue;
        float v = acc[m][n][r];
        if (EPI) {
          v += bias[gcol];
          v = (v - bnrm[gcol]) * (bng[gcol] * rsqrtf(bnrv[gcol] + BN_EPS)) + bnb[gcol];
          v = fmaxf(v, 0.f);
        }
        Cout[(size_t)grow * ldc + gcol] = f2b(v);
      }
    }
  }
  if (ATTN_H > 0) {
    int h = blockIdx.y * NWN + wc;
#pragma unroll
    for (int m = 0; m < M_REP; m++) {
#pragma unroll
      for (int r = 0; r < 4; r++) {
        float s1 = 0.f, s2 = 0.f;
#pragma unroll
        for (int n = 0; n < N_REP; n++) {
          float av = acc[m][n][r];
          int cc = n * 16 + l15;
          s1 += av * a_s[h * WN + cc];
          s2 += av * a_d[h * WN + cc];
        }
#pragma unroll
        for (int off = 1; off < 16; off <<= 1) { s1 += __shfl_xor(s1, off); s2 += __shfl_xor(s2, off); }
        int grow = bm + wr * WM + m * 16 + l4 * 4 + r;
        if (l15 == 0 && grow < M) {
          asrc[grow * ATTN_H + h] = s1;
          adst[grow * ATTN_H + h] = s2;
        }
      }
    }
  }
}

// ---------------- L1 gather in x-space ----------------
__global__ __launch_bounds__(256) void k_gather_x(
    const int* __restrict__ rowStart, const int* __restrict__ csrSrc,
    const float* __restrict__ aeC, const float* __restrict__ asrc, const float* __restrict__ adst,
    const u16* __restrict__ xbf, u16* __restrict__ aggOut, int Nn) {
  int wid = threadIdx.x >> 6;
  int n = blockIdx.x * 4 + wid;
  if (n >= Nn) return;
  int lane = threadIdx.x & 63;
  __shared__ float pbuf[4][64 * 4];
  int r0 = rowStart[n], r1 = rowStart[n + 1];
  f32x4 vaN = *(const f32x4*)(asrc + n * 4);
  f32x4 vdN = *(const f32x4*)(adst + n * 4);

  f32x4 m = {-1e30f, -1e30f, -1e30f, -1e30f};
  f32x4 denl = {0.f, 0.f, 0.f, 0.f};
  f32x4 aes = {0.f, 0.f, 0.f, 0.f};
  f32x4 acc = {0.f, 0.f, 0.f, 0.f};

  const f32x4* AE4 = (const f32x4*)aeC;
  for (int base = r0; base < r1; base += 64) {
    int slot = base + lane;
    bool valid = slot < r1;
    int srcl = 0;
    f32x4 lg = {-1e30f, -1e30f, -1e30f, -1e30f};
    if (valid) {
      srcl = csrSrc[slot];
      f32x4 vaS = *(const f32x4*)(asrc + srcl * 4);
      f32x4 ae = AE4[slot];
#pragma unroll
      for (int h = 0; h < 4; h++) { aes[h] += ae[h]; lg[h] = leaky(vaS[h] + vdN[h] + ae[h]); }
    }
    f32x4 mc = lg;
#pragma unroll
    for (int off = 1; off < 64; off <<= 1) {
#pragma unroll
      for (int h = 0; h < 4; h++) mc[h] = fmaxf(mc[h], __shfl_xor(mc[h], off));
    }
    f32x4 rr;
#pragma unroll
    for (int h = 0; h < 4; h++) {
      float mn = fmaxf(m[h], mc[h]);
      rr[h] = __expf(m[h] - mn);
      m[h] = mn;
      denl[h] *= rr[h];
      acc[h] *= rr[h];
    }
    f32x4 ex;
#pragma unroll
    for (int h = 0; h < 4; h++) ex[h] = valid ? __expf(lg[h] - m[h]) : 0.f;
#pragma unroll
    for (int h = 0; h < 4; h++) denl[h] += ex[h];
    *(f32x4*)(&pbuf[wid][lane * 4]) = ex;
    int nv = r1 - base; if (nv > 64) nv = 64;
    int j = 0;
    for (; j + 7 < nv; j += 8) {
      int ss[8];
      float xs[8];
#pragma unroll
      for (int q = 0; q < 8; q++) ss[q] = __shfl(srcl, j + q);
#pragma unroll
      for (int q = 0; q < 8; q++) xs[q] = b2f(xbf[(size_t)ss[q] * 64 + lane]);
#pragma unroll
      for (int q = 0; q < 8; q++) {
        f32x4 p = *(const f32x4*)(&pbuf[wid][(j + q) * 4]);
#pragma unroll
        for (int h = 0; h < 4; h++) acc[h] += p[h] * xs[q];
      }
    }
    for (; j < nv; j++) {
      int s0 = __shfl(srcl, j);
      f32x4 p0 = *(const f32x4*)(&pbuf[wid][j * 4]);
      float x0 = b2f(xbf[(size_t)s0 * 64 + lane]);
#pragma unroll
      for (int h = 0; h < 4; h++) acc[h] += p0[h] * x0;
    }
  }
  float degf = fmaxf((float)(r1 - r0), 1.0f);
  f32x4 ls, exs;
#pragma unroll
  for (int h = 0; h < 4; h++) {
    float a = aes[h];
#pragma unroll
    for (int off = 1; off < 64; off <<= 1) a += __shfl_xor(a, off);
    ls[h] = leaky(vaN[h] + vdN[h] + a / degf);
    float mn = fmaxf(m[h], ls[h]);
    float sc = __expf(m[h] - mn);
    m[h] = mn;
    denl[h] *= sc;
    acc[h] *= sc;
    exs[h] = __expf(ls[h] - mn);
  }
  f32x4 den;
#pragma unroll
  for (int h = 0; h < 4; h++) {
    float v = denl[h];
#pragma unroll
    for (int off = 1; off < 64; off <<= 1) v += __shfl_xor(v, off);
    den[h] = v + exs[h];
  }
  {
    float xn = b2f(xbf[(size_t)n * 64 + lane]);
#pragma unroll
    for (int h = 0; h < 4; h++) acc[h] += exs[h] * xn;
  }
#pragma unroll
  for (int h = 0; h < 4; h++) pbuf[wid][h * 64 + lane] = acc[h] / den[h];
  u16x4 ov;
#pragma unroll
  for (int jj = 0; jj < 4; jj++) ov[jj] = f2b(pbuf[wid][lane * 4 + jj]);
  *(u16x4*)(aggOut + (size_t)n * 256 + lane * 4) = ov;
}

// ---------------- gather (H=4) post-GEMM ----------------
template <int C, int CPL>
__global__ __launch_bounds__(256) void k_gather4(
    const int* __restrict__ rowStart, const int* __restrict__ csrSrc,
    const float* __restrict__ aeC, const float* __restrict__ asrc, const float* __restrict__ adst,
    const u16* __restrict__ hbuf, const float* __restrict__ bias,
    const float* __restrict__ bng, const float* __restrict__ bnb,
    const float* __restrict__ bnrm, const float* __restrict__ bnrv,
    u16* __restrict__ outbuf, int Nn) {
  constexpr int HC = 4 * C;
  typedef __attribute__((ext_vector_type(CPL))) unsigned short u16v;
  int wid = threadIdx.x >> 6;
  int n = blockIdx.x * 4 + wid;
  if (n >= Nn) return;
  int lane = threadIdx.x & 63;
  int hs = lane >> 4;
  __shared__ float pbuf[4][64 * 4];
  int r0 = rowStart[n], r1 = rowStart[n + 1];
  f32x4 vaN = *(const f32x4*)(asrc + n * 4);
  f32x4 vdN = *(const f32x4*)(adst + n * 4);

  f32x4 m = {-1e30f, -1e30f, -1e30f, -1e30f};
  f32x4 denl = {0.f, 0.f, 0.f, 0.f};
  f32x4 aes = {0.f, 0.f, 0.f, 0.f};
  float acc[CPL];
#pragma unroll
  for (int jj = 0; jj < CPL; jj++) acc[jj] = 0.f;

  const f32x4* AE4 = (const f32x4*)aeC;
  for (int base = r0; base < r1; base += 64) {
    int slot = base + lane;
    bool valid = slot < r1;
    int srcl = 0;
    f32x4 lg = {-1e30f, -1e30f, -1e30f, -1e30f};
    if (valid) {
      srcl = csrSrc[slot];
      f32x4 vaS = *(const f32x4*)(asrc + srcl * 4);
      f32x4 ae = AE4[slot];
#pragma unroll
      for (int h = 0; h < 4; h++) { aes[h] += ae[h]; lg[h] = leaky(vaS[h] + vdN[h] + ae[h]); }
    }
    f32x4 mc = lg;
#pragma unroll
    for (int off = 1; off < 64; off <<= 1) {
#pragma unroll
      for (int h = 0; h < 4; h++) mc[h] = fmaxf(mc[h], __shfl_xor(mc[h], off));
    }
    f32x4 rr;
#pragma unroll
    for (int h = 0; h < 4; h++) {
      float mn = fmaxf(m[h], mc[h]);
      rr[h] = __expf(m[h] - mn);
      m[h] = mn;
      denl[h] *= rr[h];
    }
    float rrh = sel4(rr, hs);
#pragma unroll
    for (int jj = 0; jj < CPL; jj++) acc[jj] *= rrh;
    f32x4 ex;
#pragma unroll
    for (int h = 0; h < 4; h++) ex[h] = valid ? __expf(lg[h] - m[h]) : 0.f;
#pragma unroll
    for (int h = 0; h < 4; h++) denl[h] += ex[h];
    *(f32x4*)(&pbuf[wid][lane * 4]) = ex;
    int nv = r1 - base; if (nv > 64) nv = 64;
    int j = 0;
    for (; j + 7 < nv; j += 8) {
      int ss[8];
#pragma unroll
      for (int q = 0; q < 8; q++) ss[q] = __shfl(srcl, j + q);
      u16v hv[8];
#pragma unroll
      for (int q = 0; q < 8; q++) hv[q] = *(const u16v*)(hbuf + (size_t)ss[q] * HC + lane * CPL);
#pragma unroll
      for (int q = 0; q < 8; q++) {
        float p = pbuf[wid][(j + q) * 4 + hs];
#pragma unroll
        for (int jj = 0; jj < CPL; jj++) acc[jj] += p * b2f(hv[q][jj]);
      }
    }
    for (; j < nv; j++) {
      int s0 = __shfl(srcl, j);
      float p0 = pbuf[wid][j * 4 + hs];
      u16v h0 = *(const u16v*)(hbuf + (size_t)s0 * HC + lane * CPL);
#pragma unroll
      for (int jj = 0; jj < CPL; jj++) acc[jj] += p0 * b2f(h0[jj]);
    }
  }
  float degf = fmaxf((float)(r1 - r0), 1.0f);
  f32x4 ls, exs, scv;
#pragma unroll
  for (int h = 0; h < 4; h++) {
    float a = aes[h];
#pragma unroll
    for (int off = 1; off < 64; off <<= 1) a += __shfl_xor(a, off);
    ls[h] = leaky(vaN[h] + vdN[h] + a / degf);
    float mn = fmaxf(m[h], ls[h]);
    scv[h] = __expf(m[h] - mn);
    m[h] = mn;
    denl[h] *= scv[h];
    exs[h] = __expf(ls[h] - mn);
  }
  float sch = sel4(scv, hs);
#pragma unroll
  for (int jj = 0; jj < CPL; jj++) acc[jj] *= sch;
  f32x4 den;
#pragma unroll
  for (int h = 0; h < 4; h++) {
    float v = denl[h];
#pragma unroll
    for (int off = 1; off < 64; off <<= 1) v += __shfl_xor(v, off);
    den[h] = v + exs[h];
  }
  {
    float ps = sel4(exs, hs);
    u16v hN = *(const u16v*)(hbuf + (size_t)n * HC + lane * CPL);
#pragma unroll
    for (int jj = 0; jj < CPL; jj++) acc[jj] += ps * b2f(hN[jj]);
  }
  float dh = sel4(den, hs);
  u16v ov;
#pragma unroll
  for (int jj = 0; jj < CPL; jj++) {
    int c = lane * CPL + jj;
    float v = acc[jj] / dh + bias[c];
    v = (v - bnrm[c]) * (bng[c] * rsqrtf(bnrv[c] + BN_EPS)) + bnb[c];
    ov[jj] = f2b(fmaxf(v, 0.f));
  }
  *(u16v*)(outbuf + (size_t)n * HC + lane * CPL) = ov;
}

// ---------------- gather (H=1, C=32), online single-pass ----------------
__global__ __launch_bounds__(256) void k_gather_L3(
    const int* __restrict__ rowStart, const int* __restrict__ csrSrc,
    const float* __restrict__ ae3, const float* __restrict__ asrc, const float* __restrict__ adst,
    const u16* __restrict__ hbuf, const float* __restrict__ bias,
    const float* __restrict__ bng, const float* __restrict__ bnb,
    const float* __restrict__ bnrm, const float* __restrict__ bnrv,
    u16* __restrict__ outbuf, int Nn) {
  int wid = threadIdx.x >> 6;
  int n = blockIdx.x * 4 + wid;
  if (n >= Nn) return;
  int lane = threadIdx.x & 63;
  int cl = lane & 31, half = lane >> 5;
  __shared__ float pbuf[4][64];
  int r0 = rowStart[n], r1 = rowStart[n + 1];
  float vaN = asrc[n], vdN = adst[n];

  float m = -1e30f, denl = 0.f, aes = 0.f, acc = 0.f;
  for (int base = r0; base < r1; base += 64) {
    int slot = base + lane;
    bool valid = slot < r1;
    int srcl = 0;
    float lg = -1e30f;
    if (valid) {
      srcl = csrSrc[slot];
      float ae = ae3[slot];
      aes += ae;
      lg = leaky(asrc[srcl] + vdN + ae);
    }
    float mc = lg;
#pragma unroll
    for (int off = 1; off < 64; off <<= 1) mc = fmaxf(mc, __shfl_xor(mc, off));
    float mn = fmaxf(m, mc);
    float sc = __expf(m - mn);
    m = mn;
    denl *= sc;
    acc *= sc;
    float ex = valid ? __expf(lg - m) : 0.f;
    denl += ex;
    pbuf[wid][lane] = ex;
    int nv = r1 - base; if (nv > 64) nv = 64;
    for (int j = half; j < nv; j += 2) {
      float p = pbuf[wid][j];
      int s = __shfl(srcl, j);
      acc += p * b2f(hbuf[(size_t)s * 32 + cl]);
    }
  }
#pragma unroll
  for (int off = 1; off < 64; off <<= 1) aes += __shfl_xor(aes, off);
  float degf = fmaxf((float)(r1 - r0), 1.0f);
  float ls = leaky(vaN + vdN + aes / degf);
  float mn = fmaxf(m, ls);
  float sc = __expf(m - mn);
  denl *= sc;
  acc *= sc;
  float exs = __expf(ls - mn);
#pragma unroll
  for (int off = 1; off < 64; off <<= 1) denl += __shfl_xor(denl, off);
  float den = denl + exs;
  if (half == 0) acc += exs * b2f(hbuf[(size_t)n * 32 + cl]);
  acc += __shfl_xor(acc, 32);
  if (half == 0) {
    float v = acc / den + bias[cl];
    v = (v - bnrm[cl]) * (bng[cl] * rsqrtf(bnrv[cl] + BN_EPS)) + bnb[cl];
    outbuf[(size_t)n * 32 + cl] = f2b(fmaxf(v, 0.f));
  }
}

// ---------------- fused pooling + MLP ----------------
__global__ __launch_bounds__(256) void k_pool_mlp(
    const u16* __restrict__ h3, const int* __restrict__ batch, int Nn,
    const float* __restrict__ lw1, const float* __restrict__ lb1,
    const float* __restrict__ lw2, const float* __restrict__ lb2,
    float* __restrict__ out) {
  int g = blockIdx.x;
  int tid = threadIdx.x;
  __shared__ int s_lo, s_hi;
  if (tid == 0) {
    int lo = 0, hi = Nn;
    while (lo < hi) { int mid = (lo + hi) >> 1; if (batch[mid] < g) lo = mid + 1; else hi = mid; }
    s_lo = lo;
    int lo2 = lo, hi2 = Nn;
    while (lo2 < hi2) { int mid = (lo2 + hi2) >> 1; if (batch[mid] < g + 1) lo2 = mid + 1; else hi2 = mid; }
    s_hi = lo2;
  }
  __syncthreads();
  int lo = s_lo, hi = s_hi;
  int c = tid & 31, r = tid >> 5;
  float sum = 0.f, mx = -1e30f;
  for (int n = lo + r; n < hi; n += 8) {
    float v = b2f(h3[(size_t)n * 32 + c]);
    sum += v;
    mx = fmaxf(mx, v);
  }
  __shared__ float ssum[8][32];
  __shared__ float smax[8][32];
  ssum[r][c] = sum;
  smax[r][c] = mx;
  __syncthreads();
  __shared__ float z[64];
  __shared__ float zz1[32];
  if (tid < 32) {
    float s = 0.f, m2 = -1e30f;
#pragma unroll
    for (int rr = 0; rr < 8; rr++) { s += ssum[rr][tid]; m2 = fmaxf(m2, smax[rr][tid]); }
    int cnt = hi - lo;
    z[tid] = s / fmaxf((float)cnt, 1.0f);
    z[32 + tid] = (cnt > 0) ? m2 : 0.f;
  }
  __syncthreads();
  if (tid < 32) {
    float s = lb1[tid];
    for (int k = 0; k < 64; k++) s += z[k] * lw1[k * 32 + tid];
    zz1[tid] = fmaxf(s, 0.f);
  }
  __syncthreads();
  if (tid == 0) {
    float s = lb2[0];
    for (int j = 0; j < 32; j++) s += zz1[j] * lw2[j];
    out[g] = 1.f / (1.f + expf(-s));
  }
}

// ---------------- driver ----------------
extern "C" void kernel_launch(void* const* d_in, const int* in_sizes, int n_in,
                              void* d_out, int out_size, void* d_ws, size_t ws_size,
                              hipStream_t stream) {
  const float* x     = (const float*)d_in[0];
  const int*   eidx  = (const int*)d_in[1];
  const float* eattr = (const float*)d_in[2];
  const int*   batch = (const int*)d_in[3];
  int N = in_sizes[0] / 64;
  int E = in_sizes[1] / 2;
  int NG = out_size;
  const int* src = eidx;
  const int* dst = eidx + E;

  const float* W[3]  = {(const float*)d_in[4],  (const float*)d_in[14], (const float*)d_in[24]};
  const float* AS[3] = {(const float*)d_in[5],  (const float*)d_in[15], (const float*)d_in[25]};
  const float* AD[3] = {(const float*)d_in[6],  (const float*)d_in[16], (const float*)d_in[26]};
  const float* WE[3] = {(const float*)d_in[7],  (const float*)d_in[17], (const float*)d_in[27]};
  const float* AE[3] = {(const float*)d_in[8],  (const float*)d_in[18], (const float*)d_in[28]};
  const float* B[3]  = {(const float*)d_in[9],  (const float*)d_in[19], (const float*)d_in[29]};
  const float* G[3]  = {(const float*)d_in[10], (const float*)d_in[20], (const float*)d_in[30]};
  const float* BT[3] = {(const float*)d_in[11], (const float*)d_in[21], (const float*)d_in[31]};
  const float* RM[3] = {(const float*)d_in[12], (const float*)d_in[22], (const float*)d_in[32]};
  const float* RV[3] = {(const float*)d_in[13], (const float*)d_in[23], (const float*)d_in[33]};
  const float* lw1 = (const float*)d_in[34];
  const float* lb1 = (const float*)d_in[35];
  const float* lw2 = (const float*)d_in[36];
  const float* lb2 = (const float*)d_in[37];

  char* wp = (char*)d_ws;
  auto alloc = [&](size_t bytes) -> void* {
    void* p = (void*)wp;
    wp += (bytes + 255) & ~(size_t)255;
    return p;
  };
  u16*   xbf      = (u16*)alloc((size_t)N * 64 * 2);
  u16*   aggB     = (u16*)alloc((size_t)N * 256 * 2);
  u16*   bufH     = (u16*)alloc((size_t)N * 512 * 2);
  u16*   bufA     = (u16*)alloc((size_t)N * 512 * 2);
  u16*   Wt1      = (u16*)alloc((size_t)512 * 64 * 2);
  u16*   Wt2      = (u16*)alloc((size_t)256 * 512 * 2);
  u16*   Wt3      = (u16*)alloc((size_t)32 * 256 * 2);
  int*   degInt   = (int*)alloc((size_t)N * 4);
  int*   cursor   = (int*)alloc((size_t)N * 4);
  int*   rowStart = (int*)alloc((size_t)(N + 1) * 4);
  int*   csrSrc   = (int*)alloc((size_t)E * 4);
  float* ae1      = (float*)alloc((size_t)E * 4 * 4);
  float* ae2      = (float*)alloc((size_t)E * 4 * 4);
  float* ae3buf   = (float*)alloc((size_t)E * 4);
  float* asrc     = (float*)alloc((size_t)N * 4 * 4);
  float* adst     = (float*)alloc((size_t)N * 4 * 4);
  float* watt1    = (float*)alloc(28 * 4);
  float* watt2    = (float*)alloc(28 * 4);
  float* watt3    = (float*)alloc(7 * 4);
  float* ws1      = (float*)alloc(64 * 4 * 4);
  float* wd1      = (float*)alloc(64 * 4 * 4);

  // one memset covers degInt (+pad) + cursor (adjacent allocations)
  size_t zspan = (size_t)((char*)cursor - (char*)degInt) + (size_t)N * 4;
  hipMemsetAsync(degInt, 0, zspan, stream);

  // ---- prep (weights, once)
  k_prep<<<(172352 + 255) / 256, 256, 0, stream>>>(
      W[0], W[1], W[2], AS[0], AD[0], WE[0], AE[0], WE[1], AE[1], WE[2], AE[2],
      Wt1, Wt2, Wt3, ws1, wd1, watt1, watt2, watt3);

  // ---- CSR build + fused edge-ae scatter
  k_deg<<<(E + 255) / 256, 256, 0, stream>>>(dst, degInt, E);
  k_scan<<<1, 1024, 0, stream>>>(degInt, rowStart, N);
  k_fill_csr_ae<<<(E + 255) / 256, 256, 0, stream>>>(src, dst, eattr, rowStart, cursor, csrSrc,
                                                     watt1, watt2, watt3, ae1, ae2, ae3buf, E);

  int gmM = (N + 127) / 128;
  int nb4 = (N + 3) / 4;

  // ---- layer 1: x-space aggregation, then 4 head-GEMMs with fused epilogue
  k_cast_attn_x<<<nb4, 256, 0, stream>>>(x, xbf, ws1, wd1, asrc, adst, N);
  k_gather_x<<<nb4, 256, 0, stream>>>(rowStart, csrSrc, ae1, asrc, adst, xbf, aggB, N);
  k_gemm_mfma<128, 128, 64, 64, true, 0><<<dim3(gmM, 1, 4), 256, 0, stream>>>(
      aggB, Wt1, bufA, N, 64, 128, 256, 512, 64, 128 * 64, 128,
      B[0], G[0], BT[0], RM[0], RV[0], nullptr, nullptr, nullptr, nullptr);

  // ---- layer 2: GEMM with fused attn dots (WN=64=C), then gather
  k_gemm_mfma<128, 128, 64, 64, false, 4><<<dim3(gmM, 2, 1), 256, 0, stream>>>(
      bufA, Wt2, bufH, N, 512, 256, 512, 256, 0, 0, 0,
      nullptr, nullptr, nullptr, nullptr, nullptr, AS[1], AD[1], asrc, adst);
  k_gather4<64, 4><<<nb4, 256, 0, stream>>>(rowStart, csrSrc, ae2, asrc, adst,
                                            bufH, B[1], G[1], BT[1], RM[1], RV[1], bufA, N);

  // ---- layer 3: GEMM with fused attn dots (WN=32=C, H=1), then gather
  k_gemm_mfma<128, 32, 32, 32, false, 1><<<dim3(gmM, 1, 1), 256, 0, stream>>>(
      bufA, Wt3, bufH, N, 256, 32, 256, 32, 0, 0, 0,
      nullptr, nullptr, nullptr, nullptr, nullptr, AS[2], AD[2], asrc, adst);
  k_gather_L3<<<nb4, 256, 0, stream>>>(rowStart, csrSrc, ae3buf, asrc, adst,
                                       bufH, B[2], G[2], BT[2], RM[2], RV[2], bufA, N);

  // ---- fused pooling + MLP
  k_pool_mlp<<<NG, 256, 0, stream>>>(bufA, batch, N, lw1, lb1, lw2, lb2, (float*)d_out);
}

// Round 12
// 261.492 us; speedup vs baseline: 1.7284x; 1.0332x over previous
//
#include <hip/hip_runtime.h>
#include <math.h>

#define NEG_SLOPE 0.2f
#define BN_EPS 1e-5f

typedef __attribute__((ext_vector_type(8))) short bf16x8;
typedef __attribute__((ext_vector_type(4))) float f32x4;
typedef unsigned short u16;
typedef __attribute__((ext_vector_type(4))) unsigned short u16x4;

static __device__ __forceinline__ float leaky(float v) { return v > 0.f ? v : NEG_SLOPE * v; }
static __device__ __forceinline__ float b2f(u16 b) { return __uint_as_float(((unsigned)b) << 16); }
static __device__ __forceinline__ u16 f2b(float f) {
  unsigned u = __float_as_uint(f);
  u += 0x7FFF + ((u >> 16) & 1);
  return (u16)(u >> 16);
}
static __device__ __forceinline__ float sel4(f32x4 v, int hs) {
  float a = (hs & 1) ? v[1] : v[0];
  float b = (hs & 1) ? v[3] : v[2];
  return (hs & 2) ? b : a;
}

// ---------------- prep: weight transposes + attn-weight projections ----------------
__global__ void k_prep(const float* __restrict__ W1, const float* __restrict__ W2, const float* __restrict__ W3,
                       const float* __restrict__ AS1, const float* __restrict__ AD1,
                       const float* __restrict__ WE1, const float* __restrict__ AE1,
                       const float* __restrict__ WE2, const float* __restrict__ AE2,
                       const float* __restrict__ WE3, const float* __restrict__ AE3,
                       u16* __restrict__ Wt1, u16* __restrict__ Wt2, u16* __restrict__ Wt3,
                       float* __restrict__ ws1, float* __restrict__ wd1,
                       float* __restrict__ watt1, float* __restrict__ watt2, float* __restrict__ watt3) {
  int idx = blockIdx.x * blockDim.x + threadIdx.x;
  if (idx < 32768) {                       // Wt1 [512][64] <- W1 [64][512]
    int k = idx >> 9, n = idx & 511;
    Wt1[n * 64 + k] = f2b(W1[idx]);
  } else if (idx < 163840) {               // Wt2 [256][512] <- W2 [512][256]
    int i = idx - 32768;
    int k = i >> 8, n = i & 255;
    Wt2[n * 512 + k] = f2b(W2[i]);
  } else if (idx < 172032) {               // Wt3 [32][256] <- W3 [256][32]
    int i = idx - 163840;
    int k = i >> 5, n = i & 31;
    Wt3[n * 256 + k] = f2b(W3[i]);
  } else if (idx < 172288) {               // ws1/wd1 [64][4]
    int t = idx - 172032;
    int k = t >> 2, h = t & 3;
    float s1 = 0.f, s2 = 0.f;
    for (int c = 0; c < 128; c++) {
      float w = W1[k * 512 + h * 128 + c];
      s1 += w * AS1[h * 128 + c];
      s2 += w * AD1[h * 128 + c];
    }
    ws1[t] = s1; wd1[t] = s2;
  } else if (idx < 172316) {               // watt1 [7][4]
    int t = idx - 172288;
    int d = t >> 2, h = t & 3;
    float s = 0.f;
    for (int c = 0; c < 128; c++) s += WE1[d * 512 + h * 128 + c] * AE1[h * 128 + c];
    watt1[t] = s;
  } else if (idx < 172344) {               // watt2 [7][4]
    int t = idx - 172316;
    int d = t >> 2, h = t & 3;
    float s = 0.f;
    for (int c = 0; c < 64; c++) s += WE2[d * 256 + h * 64 + c] * AE2[h * 64 + c];
    watt2[t] = s;
  } else if (idx < 172351) {               // watt3 [7]
    int d = idx - 172344;
    float s = 0.f;
    for (int c = 0; c < 32; c++) s += WE3[d * 32 + c] * AE3[c];
    watt3[d] = s;
  }
}

// ---------------- CSR build ----------------
__global__ void k_deg(const int* __restrict__ dst, int* __restrict__ degInt, int E) {
  int e = blockIdx.x * blockDim.x + threadIdx.x;
  if (e < E) atomicAdd(&degInt[dst[e]], 1);
}

__global__ void k_scan(const int* __restrict__ degInt, int* __restrict__ rowStart, int n) {
  __shared__ int sums[1024];
  int tid = threadIdx.x;
  int per = (n + 1023) / 1024;
  int start = tid * per;
  int end = start + per; if (end > n) end = n;
  int s = 0;
  for (int i = start; i < end; i++) s += degInt[i];
  sums[tid] = s;
  __syncthreads();
  for (int off = 1; off < 1024; off <<= 1) {
    int v = (tid >= off) ? sums[tid - off] : 0;
    __syncthreads();
    sums[tid] += v;
    __syncthreads();
  }
  int base = (tid > 0) ? sums[tid - 1] : 0;
  for (int i = start; i < end; i++) { rowStart[i] = base; base += degInt[i]; }
  if (tid == 1023) rowStart[n] = sums[1023];
}

// fill CSR AND scatter all 9 head ae-slots in one edge pass
__global__ void k_fill_csr_ae(const int* __restrict__ src, const int* __restrict__ dst,
                              const float* __restrict__ eattr,
                              const int* __restrict__ rowStart, int* __restrict__ cursor,
                              int* __restrict__ csrSrc,
                              const float* __restrict__ watt1, const float* __restrict__ watt2,
                              const float* __restrict__ watt3,
                              float* __restrict__ ae1, float* __restrict__ ae2,
                              float* __restrict__ ae3, int E) {
  int e = blockIdx.x * blockDim.x + threadIdx.x;
  if (e >= E) return;
  int d = dst[e];
  int pos = rowStart[d] + atomicAdd(&cursor[d], 1);
  csrSrc[pos] = src[e];
  float ea[7];
#pragma unroll
  for (int dd = 0; dd < 7; dd++) ea[dd] = eattr[e * 7 + dd];
  f32x4 o1, o2;
#pragma unroll
  for (int h = 0; h < 4; h++) {
    float a1 = 0.f, a2 = 0.f;
#pragma unroll
    for (int dd = 0; dd < 7; dd++) { a1 += ea[dd] * watt1[dd * 4 + h]; a2 += ea[dd] * watt2[dd * 4 + h]; }
    o1[h] = a1; o2[h] = a2;
  }
  float a3 = 0.f;
#pragma unroll
  for (int dd = 0; dd < 7; dd++) a3 += ea[dd] * watt3[dd];
  *(f32x4*)(ae1 + (size_t)pos * 4) = o1;
  *(f32x4*)(ae2 + (size_t)pos * 4) = o2;
  ae3[pos] = a3;
}

// ---------------- fused x cast + L1 attention dots ----------------
__global__ __launch_bounds__(256) void k_cast_attn_x(const float* __restrict__ x, u16* __restrict__ xbf,
                                                     const float* __restrict__ ws, const float* __restrict__ wd,
                                                     float* __restrict__ asrc, float* __restrict__ adst, int Nn) {
  int n = blockIdx.x * 4 + (threadIdx.x >> 6);
  if (n >= Nn) return;
  int lane = threadIdx.x & 63;
  float xv = x[(size_t)n * 64 + lane];
  xbf[(size_t)n * 64 + lane] = f2b(xv);
  f32x4 vs = *(const f32x4*)(ws + lane * 4);
  f32x4 vd = *(const f32x4*)(wd + lane * 4);
  f32x4 s1, s2;
#pragma unroll
  for (int h = 0; h < 4; h++) { s1[h] = xv * vs[h]; s2[h] = xv * vd[h]; }
#pragma unroll
  for (int off = 1; off < 64; off <<= 1) {
#pragma unroll
    for (int h = 0; h < 4; h++) { s1[h] += __shfl_xor(s1[h], off); s2[h] += __shfl_xor(s2[h], off); }
  }
  if (lane == 0) {
    *(f32x4*)(asrc + n * 4) = s1;
    *(f32x4*)(adst + n * 4) = s2;
  }
}

// ---------------- MFMA bf16 GEMM with optional epilogue / fused attn dots ----------------
template <int BM, int BN, int WM, int WN, bool EPI, int ATTN_H>
__global__ __launch_bounds__(256) void k_gemm_mfma(const u16* __restrict__ A,
                                                   const u16* __restrict__ Bt,
                                                   u16* __restrict__ Cout,
                                                   int M, int K, int Nc, int lda, int ldc,
                                                   int AzOff, int BzOff, int CzOff,
                                                   const float* __restrict__ bias,
                                                   const float* __restrict__ bng,
                                                   const float* __restrict__ bnb,
                                                   const float* __restrict__ bnrm,
                                                   const float* __restrict__ bnrv,
                                                   const float* __restrict__ a_s,
                                                   const float* __restrict__ a_d,
                                                   float* __restrict__ asrc,
                                                   float* __restrict__ adst) {
  constexpr int BK = 64;
  constexpr int LDT = BK + 8;
  __shared__ u16 As[BM][LDT];
  __shared__ u16 Bs[BN][LDT];
  constexpr int NWN = BN / WN;
  constexpr int M_REP = WM / 16;
  constexpr int N_REP = WN / 16;
  int z = blockIdx.z;
  A += (size_t)z * AzOff;
  Bt += (size_t)z * BzOff;
  Cout += (size_t)z * CzOff;
  if (EPI) {
    bias += (size_t)z * CzOff; bng += (size_t)z * CzOff; bnb += (size_t)z * CzOff;
    bnrm += (size_t)z * CzOff; bnrv += (size_t)z * CzOff;
  }
  int tid = threadIdx.x;
  int wid = tid >> 6, lane = tid & 63;
  int wr = wid / NWN, wc = wid % NWN;
  int bm = blockIdx.x * BM, bn = blockIdx.y * BN;
  int l15 = lane & 15, l4 = lane >> 4;

  f32x4 acc[M_REP][N_REP];
#pragma unroll
  for (int m = 0; m < M_REP; m++)
#pragma unroll
    for (int n = 0; n < N_REP; n++) acc[m][n] = (f32x4){0.f, 0.f, 0.f, 0.f};

  for (int k0 = 0; k0 < K; k0 += BK) {
    constexpr int CHA = BM * BK / 8;
#pragma unroll
    for (int ch0 = 0; ch0 < CHA; ch0 += 256) {
      int ch = ch0 + tid;
      int row = ch >> 3, cc = (ch & 7) * 8;
      int gr = bm + row;
      bf16x8 v = {};
      if (gr < M) v = *(const bf16x8*)(A + (size_t)gr * lda + k0 + cc);
      *(bf16x8*)(&As[row][cc]) = v;
    }
    constexpr int CHB = BN * BK / 8;
#pragma unroll
    for (int ch0 = 0; ch0 < CHB; ch0 += 256) {
      int ch = ch0 + tid;
      int row = ch >> 3, cc = (ch & 7) * 8;
      int gr = bn + row;
      bf16x8 v = {};
      if (gr < Nc) v = *(const bf16x8*)(Bt + (size_t)gr * K + k0 + cc);
      *(bf16x8*)(&Bs[row][cc]) = v;
    }
    __syncthreads();
#pragma unroll
    for (int ks = 0; ks < BK; ks += 32) {
      bf16x8 af[M_REP], bfr[N_REP];
#pragma unroll
      for (int m = 0; m < M_REP; m++)
        af[m] = *(const bf16x8*)(&As[wr * WM + m * 16 + l15][ks + l4 * 8]);
#pragma unroll
      for (int n = 0; n < N_REP; n++)
        bfr[n] = *(const bf16x8*)(&Bs[wc * WN + n * 16 + l15][ks + l4 * 8]);
#pragma unroll
      for (int m = 0; m < M_REP; m++)
#pragma unroll
        for (int n = 0; n < N_REP; n++)
          acc[m][n] = __builtin_amdgcn_mfma_f32_16x16x32_bf16(af[m], bfr[n], acc[m][n], 0, 0, 0);
    }
    __syncthreads();
  }
#pragma unroll
  for (int m = 0; m < M_REP; m++) {
#pragma unroll
    for (int r = 0; r < 4; r++) {
      int grow = bm + wr * WM + m * 16 + l4 * 4 + r;
      if (grow >= M) continue;
#pragma unroll
      for (int n = 0; n < N_REP; n++) {
        int gcol = bn + wc * WN + n * 16 + l15;
        if (gcol >= Nc) continue;
        float v = acc[m][n][r];
        if (EPI) {
          v += bias[gcol];
          v = (v - bnrm[gcol]) * (bng[gcol] * rsqrtf(bnrv[gcol] + BN_EPS)) + bnb[gcol];
          v = fmaxf(v, 0.f);
        }
        Cout[(size_t)grow * ldc + gcol] = f2b(v);
      }
    }
  }
  if (ATTN_H > 0) {
    int h = blockIdx.y * NWN + wc;
#pragma unroll
    for (int m = 0; m < M_REP; m++) {
#pragma unroll
      for (int r = 0; r < 4; r++) {
        float s1 = 0.f, s2 = 0.f;
#pragma unroll
        for (int n = 0; n < N_REP; n++) {
          float av = acc[m][n][r];
          int cc = n * 16 + l15;
          s1 += av * a_s[h * WN + cc];
          s2 += av * a_d[h * WN + cc];
        }
#pragma unroll
        for (int off = 1; off < 16; off <<= 1) { s1 += __shfl_xor(s1, off); s2 += __shfl_xor(s2, off); }
        int grow = bm + wr * WM + m * 16 + l4 * 4 + r;
        if (l15 == 0 && grow < M) {
          asrc[grow * ATTN_H + h] = s1;
          adst[grow * ATTN_H + h] = s2;
        }
      }
    }
  }
}

// ---------------- L1 gather in x-space (x4-deep) ----------------
__global__ __launch_bounds__(256) void k_gather_x(
    const int* __restrict__ rowStart, const int* __restrict__ csrSrc,
    const float* __restrict__ aeC, const float* __restrict__ asrc, const float* __restrict__ adst,
    const u16* __restrict__ xbf, u16* __restrict__ aggOut, int Nn) {
  int wid = threadIdx.x >> 6;
  int n = blockIdx.x * 4 + wid;
  if (n >= Nn) return;
  int lane = threadIdx.x & 63;
  __shared__ float pbuf[4][64 * 4];
  int r0 = rowStart[n], r1 = rowStart[n + 1];
  f32x4 vaN = *(const f32x4*)(asrc + n * 4);
  f32x4 vdN = *(const f32x4*)(adst + n * 4);

  f32x4 m = {-1e30f, -1e30f, -1e30f, -1e30f};
  f32x4 denl = {0.f, 0.f, 0.f, 0.f};
  f32x4 aes = {0.f, 0.f, 0.f, 0.f};
  f32x4 acc = {0.f, 0.f, 0.f, 0.f};

  const f32x4* AE4 = (const f32x4*)aeC;
  for (int base = r0; base < r1; base += 64) {
    int slot = base + lane;
    bool valid = slot < r1;
    int srcl = 0;
    f32x4 lg = {-1e30f, -1e30f, -1e30f, -1e30f};
    if (valid) {
      srcl = csrSrc[slot];
      f32x4 vaS = *(const f32x4*)(asrc + srcl * 4);
      f32x4 ae = AE4[slot];
#pragma unroll
      for (int h = 0; h < 4; h++) { aes[h] += ae[h]; lg[h] = leaky(vaS[h] + vdN[h] + ae[h]); }
    }
    f32x4 mc = lg;
#pragma unroll
    for (int off = 1; off < 64; off <<= 1) {
#pragma unroll
      for (int h = 0; h < 4; h++) mc[h] = fmaxf(mc[h], __shfl_xor(mc[h], off));
    }
    f32x4 rr;
#pragma unroll
    for (int h = 0; h < 4; h++) {
      float mn = fmaxf(m[h], mc[h]);
      rr[h] = __expf(m[h] - mn);
      m[h] = mn;
      denl[h] *= rr[h];
      acc[h] *= rr[h];
    }
    f32x4 ex;
#pragma unroll
    for (int h = 0; h < 4; h++) ex[h] = valid ? __expf(lg[h] - m[h]) : 0.f;
#pragma unroll
    for (int h = 0; h < 4; h++) denl[h] += ex[h];
    *(f32x4*)(&pbuf[wid][lane * 4]) = ex;
    int nv = r1 - base; if (nv > 64) nv = 64;
    int j = 0;
    for (; j + 3 < nv; j += 4) {
      int s0 = __shfl(srcl, j);
      int s1 = __shfl(srcl, j + 1);
      int s2 = __shfl(srcl, j + 2);
      int s3 = __shfl(srcl, j + 3);
      f32x4 p0 = *(const f32x4*)(&pbuf[wid][j * 4]);
      f32x4 p1 = *(const f32x4*)(&pbuf[wid][(j + 1) * 4]);
      f32x4 p2 = *(const f32x4*)(&pbuf[wid][(j + 2) * 4]);
      f32x4 p3 = *(const f32x4*)(&pbuf[wid][(j + 3) * 4]);
      float x0 = b2f(xbf[(size_t)s0 * 64 + lane]);
      float x1 = b2f(xbf[(size_t)s1 * 64 + lane]);
      float x2 = b2f(xbf[(size_t)s2 * 64 + lane]);
      float x3 = b2f(xbf[(size_t)s3 * 64 + lane]);
#pragma unroll
      for (int h = 0; h < 4; h++)
        acc[h] += p0[h] * x0 + p1[h] * x1 + p2[h] * x2 + p3[h] * x3;
    }
    for (; j < nv; j++) {
      int s0 = __shfl(srcl, j);
      f32x4 p0 = *(const f32x4*)(&pbuf[wid][j * 4]);
      float x0 = b2f(xbf[(size_t)s0 * 64 + lane]);
#pragma unroll
      for (int h = 0; h < 4; h++) acc[h] += p0[h] * x0;
    }
  }
  float degf = fmaxf((float)(r1 - r0), 1.0f);
  f32x4 ls, exs;
#pragma unroll
  for (int h = 0; h < 4; h++) {
    float a = aes[h];
#pragma unroll
    for (int off = 1; off < 64; off <<= 1) a += __shfl_xor(a, off);
    ls[h] = leaky(vaN[h] + vdN[h] + a / degf);
    float mn = fmaxf(m[h], ls[h]);
    float sc = __expf(m[h] - mn);
    m[h] = mn;
    denl[h] *= sc;
    acc[h] *= sc;
    exs[h] = __expf(ls[h] - mn);
  }
  f32x4 den;
#pragma unroll
  for (int h = 0; h < 4; h++) {
    float v = denl[h];
#pragma unroll
    for (int off = 1; off < 64; off <<= 1) v += __shfl_xor(v, off);
    den[h] = v + exs[h];
  }
  {
    float xn = b2f(xbf[(size_t)n * 64 + lane]);
#pragma unroll
    for (int h = 0; h < 4; h++) acc[h] += exs[h] * xn;
  }
#pragma unroll
  for (int h = 0; h < 4; h++) pbuf[wid][h * 64 + lane] = acc[h] / den[h];
  u16x4 ov;
#pragma unroll
  for (int jj = 0; jj < 4; jj++) ov[jj] = f2b(pbuf[wid][lane * 4 + jj]);
  *(u16x4*)(aggOut + (size_t)n * 256 + lane * 4) = ov;
}

// ---------------- gather (H=4) post-GEMM (x4-deep) ----------------
template <int C, int CPL>
__global__ __launch_bounds__(256) void k_gather4(
    const int* __restrict__ rowStart, const int* __restrict__ csrSrc,
    const float* __restrict__ aeC, const float* __restrict__ asrc, const float* __restrict__ adst,
    const u16* __restrict__ hbuf, const float* __restrict__ bias,
    const float* __restrict__ bng, const float* __restrict__ bnb,
    const float* __restrict__ bnrm, const float* __restrict__ bnrv,
    u16* __restrict__ outbuf, int Nn) {
  constexpr int HC = 4 * C;
  typedef __attribute__((ext_vector_type(CPL))) unsigned short u16v;
  int wid = threadIdx.x >> 6;
  int n = blockIdx.x * 4 + wid;
  if (n >= Nn) return;
  int lane = threadIdx.x & 63;
  int hs = lane >> 4;
  __shared__ float pbuf[4][64 * 4];
  int r0 = rowStart[n], r1 = rowStart[n + 1];
  f32x4 vaN = *(const f32x4*)(asrc + n * 4);
  f32x4 vdN = *(const f32x4*)(adst + n * 4);

  f32x4 m = {-1e30f, -1e30f, -1e30f, -1e30f};
  f32x4 denl = {0.f, 0.f, 0.f, 0.f};
  f32x4 aes = {0.f, 0.f, 0.f, 0.f};
  float acc[CPL];
#pragma unroll
  for (int jj = 0; jj < CPL; jj++) acc[jj] = 0.f;

  const f32x4* AE4 = (const f32x4*)aeC;
  for (int base = r0; base < r1; base += 64) {
    int slot = base + lane;
    bool valid = slot < r1;
    int srcl = 0;
    f32x4 lg = {-1e30f, -1e30f, -1e30f, -1e30f};
    if (valid) {
      srcl = csrSrc[slot];
      f32x4 vaS = *(const f32x4*)(asrc + srcl * 4);
      f32x4 ae = AE4[slot];
#pragma unroll
      for (int h = 0; h < 4; h++) { aes[h] += ae[h]; lg[h] = leaky(vaS[h] + vdN[h] + ae[h]); }
    }
    f32x4 mc = lg;
#pragma unroll
    for (int off = 1; off < 64; off <<= 1) {
#pragma unroll
      for (int h = 0; h < 4; h++) mc[h] = fmaxf(mc[h], __shfl_xor(mc[h], off));
    }
    f32x4 rr;
#pragma unroll
    for (int h = 0; h < 4; h++) {
      float mn = fmaxf(m[h], mc[h]);
      rr[h] = __expf(m[h] - mn);
      m[h] = mn;
      denl[h] *= rr[h];
    }
    float rrh = sel4(rr, hs);
#pragma unroll
    for (int jj = 0; jj < CPL; jj++) acc[jj] *= rrh;
    f32x4 ex;
#pragma unroll
    for (int h = 0; h < 4; h++) ex[h] = valid ? __expf(lg[h] - m[h]) : 0.f;
#pragma unroll
    for (int h = 0; h < 4; h++) denl[h] += ex[h];
    *(f32x4*)(&pbuf[wid][lane * 4]) = ex;
    int nv = r1 - base; if (nv > 64) nv = 64;
    int j = 0;
    for (; j + 3 < nv; j += 4) {
      int s0 = __shfl(srcl, j);
      int s1 = __shfl(srcl, j + 1);
      int s2 = __shfl(srcl, j + 2);
      int s3 = __shfl(srcl, j + 3);
      float p0 = pbuf[wid][j * 4 + hs];
      float p1 = pbuf[wid][(j + 1) * 4 + hs];
      float p2 = pbuf[wid][(j + 2) * 4 + hs];
      float p3 = pbuf[wid][(j + 3) * 4 + hs];
      u16v h0 = *(const u16v*)(hbuf + (size_t)s0 * HC + lane * CPL);
      u16v h1 = *(const u16v*)(hbuf + (size_t)s1 * HC + lane * CPL);
      u16v h2 = *(const u16v*)(hbuf + (size_t)s2 * HC + lane * CPL);
      u16v h3 = *(const u16v*)(hbuf + (size_t)s3 * HC + lane * CPL);
#pragma unroll
      for (int jj = 0; jj < CPL; jj++)
        acc[jj] += p0 * b2f(h0[jj]) + p1 * b2f(h1[jj]) + p2 * b2f(h2[jj]) + p3 * b2f(h3[jj]);
    }
    for (; j < nv; j++) {
      int s0 = __shfl(srcl, j);
      float p0 = pbuf[wid][j * 4 + hs];
      u16v h0 = *(const u16v*)(hbuf + (size_t)s0 * HC + lane * CPL);
#pragma unroll
      for (int jj = 0; jj < CPL; jj++) acc[jj] += p0 * b2f(h0[jj]);
    }
  }
  float degf = fmaxf((float)(r1 - r0), 1.0f);
  f32x4 ls, exs, scv;
#pragma unroll
  for (int h = 0; h < 4; h++) {
    float a = aes[h];
#pragma unroll
    for (int off = 1; off < 64; off <<= 1) a += __shfl_xor(a, off);
    ls[h] = leaky(vaN[h] + vdN[h] + a / degf);
    float mn = fmaxf(m[h], ls[h]);
    scv[h] = __expf(m[h] - mn);
    m[h] = mn;
    denl[h] *= scv[h];
    exs[h] = __expf(ls[h] - mn);
  }
  float sch = sel4(scv, hs);
#pragma unroll
  for (int jj = 0; jj < CPL; jj++) acc[jj] *= sch;
  f32x4 den;
#pragma unroll
  for (int h = 0; h < 4; h++) {
    float v = denl[h];
#pragma unroll
    for (int off = 1; off < 64; off <<= 1) v += __shfl_xor(v, off);
    den[h] = v + exs[h];
  }
  {
    float ps = sel4(exs, hs);
    u16v hN = *(const u16v*)(hbuf + (size_t)n * HC + lane * CPL);
#pragma unroll
    for (int jj = 0; jj < CPL; jj++) acc[jj] += ps * b2f(hN[jj]);
  }
  float dh = sel4(den, hs);
  u16v ov;
#pragma unroll
  for (int jj = 0; jj < CPL; jj++) {
    int c = lane * CPL + jj;
    float v = acc[jj] / dh + bias[c];
    v = (v - bnrm[c]) * (bng[c] * rsqrtf(bnrv[c] + BN_EPS)) + bnb[c];
    ov[jj] = f2b(fmaxf(v, 0.f));
  }
  *(u16v*)(outbuf + (size_t)n * HC + lane * CPL) = ov;
}

// ---------------- gather (H=1, C=32), online single-pass ----------------
__global__ __launch_bounds__(256) void k_gather_L3(
    const int* __restrict__ rowStart, const int* __restrict__ csrSrc,
    const float* __restrict__ ae3, const float* __restrict__ asrc, const float* __restrict__ adst,
    const u16* __restrict__ hbuf, const float* __restrict__ bias,
    const float* __restrict__ bng, const float* __restrict__ bnb,
    const float* __restrict__ bnrm, const float* __restrict__ bnrv,
    u16* __restrict__ outbuf, int Nn) {
  int wid = threadIdx.x >> 6;
  int n = blockIdx.x * 4 + wid;
  if (n >= Nn) return;
  int lane = threadIdx.x & 63;
  int cl = lane & 31, half = lane >> 5;
  __shared__ float pbuf[4][64];
  int r0 = rowStart[n], r1 = rowStart[n + 1];
  float vaN = asrc[n], vdN = adst[n];

  float m = -1e30f, denl = 0.f, aes = 0.f, acc = 0.f;
  for (int base = r0; base < r1; base += 64) {
    int slot = base + lane;
    bool valid = slot < r1;
    int srcl = 0;
    float lg = -1e30f;
    if (valid) {
      srcl = csrSrc[slot];
      float ae = ae3[slot];
      aes += ae;
      lg = leaky(asrc[srcl] + vdN + ae);
    }
    float mc = lg;
#pragma unroll
    for (int off = 1; off < 64; off <<= 1) mc = fmaxf(mc, __shfl_xor(mc, off));
    float mn = fmaxf(m, mc);
    float sc = __expf(m - mn);
    m = mn;
    denl *= sc;
    acc *= sc;
    float ex = valid ? __expf(lg - m) : 0.f;
    denl += ex;
    pbuf[wid][lane] = ex;
    int nv = r1 - base; if (nv > 64) nv = 64;
    for (int j = half; j < nv; j += 2) {
      float p = pbuf[wid][j];
      int s = __shfl(srcl, j);
      acc += p * b2f(hbuf[(size_t)s * 32 + cl]);
    }
  }
#pragma unroll
  for (int off = 1; off < 64; off <<= 1) aes += __shfl_xor(aes, off);
  float degf = fmaxf((float)(r1 - r0), 1.0f);
  float ls = leaky(vaN + vdN + aes / degf);
  float mn = fmaxf(m, ls);
  float sc = __expf(m - mn);
  denl *= sc;
  acc *= sc;
  float exs = __expf(ls - mn);
#pragma unroll
  for (int off = 1; off < 64; off <<= 1) denl += __shfl_xor(denl, off);
  float den = denl + exs;
  if (half == 0) acc += exs * b2f(hbuf[(size_t)n * 32 + cl]);
  acc += __shfl_xor(acc, 32);
  if (half == 0) {
    float v = acc / den + bias[cl];
    v = (v - bnrm[cl]) * (bng[cl] * rsqrtf(bnrv[cl] + BN_EPS)) + bnb[cl];
    outbuf[(size_t)n * 32 + cl] = f2b(fmaxf(v, 0.f));
  }
}

// ---------------- fused pooling + MLP ----------------
__global__ __launch_bounds__(256) void k_pool_mlp(
    const u16* __restrict__ h3, const int* __restrict__ batch, int Nn,
    const float* __restrict__ lw1, const float* __restrict__ lb1,
    const float* __restrict__ lw2, const float* __restrict__ lb2,
    float* __restrict__ out) {
  int g = blockIdx.x;
  int tid = threadIdx.x;
  __shared__ int s_lo, s_hi;
  if (tid == 0) {
    int lo = 0, hi = Nn;
    while (lo < hi) { int mid = (lo + hi) >> 1; if (batch[mid] < g) lo = mid + 1; else hi = mid; }
    s_lo = lo;
    int lo2 = lo, hi2 = Nn;
    while (lo2 < hi2) { int mid = (lo2 + hi2) >> 1; if (batch[mid] < g + 1) lo2 = mid + 1; else hi2 = mid; }
    s_hi = lo2;
  }
  __syncthreads();
  int lo = s_lo, hi = s_hi;
  int c = tid & 31, r = tid >> 5;
  float sum = 0.f, mx = -1e30f;
  for (int n = lo + r; n < hi; n += 8) {
    float v = b2f(h3[(size_t)n * 32 + c]);
    sum += v;
    mx = fmaxf(mx, v);
  }
  __shared__ float ssum[8][32];
  __shared__ float smax[8][32];
  ssum[r][c] = sum;
  smax[r][c] = mx;
  __syncthreads();
  __shared__ float z[64];
  __shared__ float zz1[32];
  if (tid < 32) {
    float s = 0.f, m2 = -1e30f;
#pragma unroll
    for (int rr = 0; rr < 8; rr++) { s += ssum[rr][tid]; m2 = fmaxf(m2, smax[rr][tid]); }
    int cnt = hi - lo;
    z[tid] = s / fmaxf((float)cnt, 1.0f);
    z[32 + tid] = (cnt > 0) ? m2 : 0.f;
  }
  __syncthreads();
  if (tid < 32) {
    float s = lb1[tid];
    for (int k = 0; k < 64; k++) s += z[k] * lw1[k * 32 + tid];
    zz1[tid] = fmaxf(s, 0.f);
  }
  __syncthreads();
  if (tid == 0) {
    float s = lb2[0];
    for (int j = 0; j < 32; j++) s += zz1[j] * lw2[j];
    out[g] = 1.f / (1.f + expf(-s));
  }
}

// ---------------- driver ----------------
extern "C" void kernel_launch(void* const* d_in, const int* in_sizes, int n_in,
                              void* d_out, int out_size, void* d_ws, size_t ws_size,
                              hipStream_t stream) {
  const float* x     = (const float*)d_in[0];
  const int*   eidx  = (const int*)d_in[1];
  const float* eattr = (const float*)d_in[2];
  const int*   batch = (const int*)d_in[3];
  int N = in_sizes[0] / 64;
  int E = in_sizes[1] / 2;
  int NG = out_size;
  const int* src = eidx;
  const int* dst = eidx + E;

  const float* W[3]  = {(const float*)d_in[4],  (const float*)d_in[14], (const float*)d_in[24]};
  const float* AS[3] = {(const float*)d_in[5],  (const float*)d_in[15], (const float*)d_in[25]};
  const float* AD[3] = {(const float*)d_in[6],  (const float*)d_in[16], (const float*)d_in[26]};
  const float* WE[3] = {(const float*)d_in[7],  (const float*)d_in[17], (const float*)d_in[27]};
  const float* AE[3] = {(const float*)d_in[8],  (const float*)d_in[18], (const float*)d_in[28]};
  const float* B[3]  = {(const float*)d_in[9],  (const float*)d_in[19], (const float*)d_in[29]};
  const float* G[3]  = {(const float*)d_in[10], (const float*)d_in[20], (const float*)d_in[30]};
  const float* BT[3] = {(const float*)d_in[11], (const float*)d_in[21], (const float*)d_in[31]};
  const float* RM[3] = {(const float*)d_in[12], (const float*)d_in[22], (const float*)d_in[32]};
  const float* RV[3] = {(const float*)d_in[13], (const float*)d_in[23], (const float*)d_in[33]};
  const float* lw1 = (const float*)d_in[34];
  const float* lb1 = (const float*)d_in[35];
  const float* lw2 = (const float*)d_in[36];
  const float* lb2 = (const float*)d_in[37];

  char* wp = (char*)d_ws;
  auto alloc = [&](size_t bytes) -> void* {
    void* p = (void*)wp;
    wp += (bytes + 255) & ~(size_t)255;
    return p;
  };
  u16*   xbf      = (u16*)alloc((size_t)N * 64 * 2);
  u16*   aggB     = (u16*)alloc((size_t)N * 256 * 2);
  u16*   bufH     = (u16*)alloc((size_t)N * 512 * 2);
  u16*   bufA     = (u16*)alloc((size_t)N * 512 * 2);
  u16*   Wt1      = (u16*)alloc((size_t)512 * 64 * 2);
  u16*   Wt2      = (u16*)alloc((size_t)256 * 512 * 2);
  u16*   Wt3      = (u16*)alloc((size_t)32 * 256 * 2);
  int*   degInt   = (int*)alloc((size_t)N * 4);
  int*   cursor   = (int*)alloc((size_t)N * 4);
  int*   rowStart = (int*)alloc((size_t)(N + 1) * 4);
  int*   csrSrc   = (int*)alloc((size_t)E * 4);
  float* ae1      = (float*)alloc((size_t)E * 4 * 4);
  float* ae2      = (float*)alloc((size_t)E * 4 * 4);
  float* ae3buf   = (float*)alloc((size_t)E * 4);
  float* asrc     = (float*)alloc((size_t)N * 4 * 4);
  float* adst     = (float*)alloc((size_t)N * 4 * 4);
  float* watt1    = (float*)alloc(28 * 4);
  float* watt2    = (float*)alloc(28 * 4);
  float* watt3    = (float*)alloc(7 * 4);
  float* ws1      = (float*)alloc(64 * 4 * 4);
  float* wd1      = (float*)alloc(64 * 4 * 4);

  // one memset covers degInt (+pad) + cursor (adjacent allocations)
  size_t zspan = (size_t)((char*)cursor - (char*)degInt) + (size_t)N * 4;
  hipMemsetAsync(degInt, 0, zspan, stream);

  // ---- prep (weights, once)
  k_prep<<<(172352 + 255) / 256, 256, 0, stream>>>(
      W[0], W[1], W[2], AS[0], AD[0], WE[0], AE[0], WE[1], AE[1], WE[2], AE[2],
      Wt1, Wt2, Wt3, ws1, wd1, watt1, watt2, watt3);

  // ---- CSR build + fused edge-ae scatter
  k_deg<<<(E + 255) / 256, 256, 0, stream>>>(dst, degInt, E);
  k_scan<<<1, 1024, 0, stream>>>(degInt, rowStart, N);
  k_fill_csr_ae<<<(E + 255) / 256, 256, 0, stream>>>(src, dst, eattr, rowStart, cursor, csrSrc,
                                                     watt1, watt2, watt3, ae1, ae2, ae3buf, E);

  int gmM = (N + 127) / 128;
  int nb4 = (N + 3) / 4;

  // ---- layer 1: x-space aggregation, then 4 head-GEMMs with fused epilogue
  k_cast_attn_x<<<nb4, 256, 0, stream>>>(x, xbf, ws1, wd1, asrc, adst, N);
  k_gather_x<<<nb4, 256, 0, stream>>>(rowStart, csrSrc, ae1, asrc, adst, xbf, aggB, N);
  k_gemm_mfma<128, 128, 64, 64, true, 0><<<dim3(gmM, 1, 4), 256, 0, stream>>>(
      aggB, Wt1, bufA, N, 64, 128, 256, 512, 64, 128 * 64, 128,
      B[0], G[0], BT[0], RM[0], RV[0], nullptr, nullptr, nullptr, nullptr);

  // ---- layer 2: GEMM with fused attn dots (WN=64=C), then gather
  k_gemm_mfma<128, 128, 64, 64, false, 4><<<dim3(gmM, 2, 1), 256, 0, stream>>>(
      bufA, Wt2, bufH, N, 512, 256, 512, 256, 0, 0, 0,
      nullptr, nullptr, nullptr, nullptr, nullptr, AS[1], AD[1], asrc, adst);
  k_gather4<64, 4><<<nb4, 256, 0, stream>>>(rowStart, csrSrc, ae2, asrc, adst,
                                            bufH, B[1], G[1], BT[1], RM[1], RV[1], bufA, N);

  // ---- layer 3: GEMM with fused attn dots (WN=32=C, H=1), then gather
  k_gemm_mfma<128, 32, 32, 32, false, 1><<<dim3(gmM, 1, 1), 256, 0, stream>>>(
      bufA, Wt3, bufH, N, 256, 32, 256, 32, 0, 0, 0,
      nullptr, nullptr, nullptr, nullptr, nullptr, AS[2], AD[2], asrc, adst);
  k_gather_L3<<<nb4, 256, 0, stream>>>(rowStart, csrSrc, ae3buf, asrc, adst,
                                       bufH, B[2], G[2], BT[2], RM[2], RV[2], bufA, N);

  // ---- fused pooling + MLP
  k_pool_mlp<<<NG, 256, 0, stream>>>(bufA, batch, N, lw1, lb1, lw2, lb2, (float*)d_out);
}